// Round 13
// baseline (488.343 us; speedup 1.0000x reference)
//
#include <hip/hip_runtime.h>

#define N_PTS 4096
#define NB    8
#define KNN   20
#define FIN   67
#define COUT  64
#define SEG   4
#define SEGN  (N_PTS / SEG)   // 1024 candidates per segment-thread
#define SLOTS 24              // LDS stack slots per thread

typedef unsigned short u16;
typedef unsigned int   u32;
typedef unsigned long long u64;

__device__ __forceinline__ float finf() { return __uint_as_float(0x7f800000u); }

// sq = (x*x + y*y) + z*z, all f32, no FMA (matches np op order).
__device__ __forceinline__ float sq_exact(float x, float y, float z) {
#pragma clang fp contract(off)
    float s = (x * x + y * y) + z * z;
    return s;
}

// dist = (sq_i - 2*dot) + sq_j, dot = (x_i*x_j + y_i*y_j) + z_i*z_j, no FMA.
__device__ __forceinline__ float dist_from_sq(float xi, float yi, float zi, float sqi,
                                              float xj, float yj, float zj, float sqj) {
#pragma clang fp contract(off)
    float d0 = xi * xj, d1 = yi * yj, d2 = zi * zj;
    float dot = (d0 + d1) + d2;
    float d = (sqi - 2.0f * dot) + sqj;
    return d;
}

__device__ __forceinline__ float dist_exact(float xi, float yi, float zi, float sqi,
                                            float xj, float yj, float zj) {
#pragma clang fp contract(off)
    float d0 = xi * xj, d1 = yi * yj, d2 = zi * zj;
    float dot = (d0 + d1) + d2;
    float sqj = (xj * xj + yj * yj) + zj * zj;
    float d = (sqi - 2.0f * dot) + sqj;
    return d;
}

// Compare-exchange on (d, j) lexicographic (strict) — matches lax.top_k order.
__device__ __forceinline__ void cswap(float& ad, u32& aj, float& bd, u32& bj) {
    bool sw = (bd < ad) || ((bd == ad) && (bj < aj));
    float nad = sw ? bd : ad, nbd = sw ? ad : bd;
    u32   naj = sw ? bj : aj, nbj = sw ? aj : bj;
    ad = nad; bd = nbd; aj = naj; bj = nbj;
}

// ---------------- Kernel 1: kNN, (query, segment) per thread ----------------
// Block = 256 threads = 64 queries x 4 segments of 1024 candidates.
// LDS stacks are SoA [slot][thread]: bank = tid mod 32 -> 2 lanes/bank = FREE
// (round-12 layout was [thread][slot], stride 192 B -> 32-way conflict,
// 7.15M SQ_LDS_BANK_CONFLICT -> this is the fix).
__global__ __launch_bounds__(256) void knn_seg_kernel(
    const float* __restrict__ xloc, u16* __restrict__ knn_out) {
    __shared__ float stkd[SLOTS][256];        // 24 KB
    __shared__ u32   stkj[SLOTS][256];        // 24 KB
    const int tid  = threadIdx.x;
    const int lane = tid & 63;                // query within tile
    const int seg  = tid >> 6;                // candidate segment (wave-uniform)
    const int blk  = blockIdx.x;              // b*64 + qtile
    const int b    = blk >> 6;
    const int i    = ((blk & 63) << 6) | lane;
    const float* xb = xloc + (size_t)b * 3 * N_PTS;

    const float xi = xb[i], yi = xb[N_PTS + i], zi = xb[2 * N_PTS + i];
    const float sqi = sq_exact(xi, yi, zi);

    float ld[32]; u32 lj[32];
#pragma unroll
    for (int t = 0; t < 32; ++t) { ld[t] = finf(); lj[t] = 0xFFFFFFFFu; }
    float thr = finf();
    int cnt = 0;

    // Merge the stack (cnt valid of SLOTS) into sorted 32-list, keep 32 smallest.
    auto merge_stack = [&]() {
        float bd[32]; u32 bj[32];
#pragma unroll
        for (int t = 0; t < SLOTS; ++t) {
            bool valid = t < cnt;
            bd[t] = valid ? stkd[t][tid] : finf();
            bj[t] = valid ? stkj[t][tid] : 0xFFFFFFFFu;
        }
#pragma unroll
        for (int t = SLOTS; t < 32; ++t) { bd[t] = finf(); bj[t] = 0xFFFFFFFFu; }

        // Bitonic sort 32 ascending (static indices only).
#pragma unroll
        for (int k = 2; k <= 32; k <<= 1) {
#pragma unroll
            for (int s = k >> 1; s > 0; s >>= 1) {
#pragma unroll
                for (int t = 0; t < 32; ++t) {
                    int l = t ^ s;
                    if (l > t) {
                        if ((t & k) == 0) cswap(bd[t], bj[t], bd[l], bj[l]);
                        else              cswap(bd[l], bj[l], bd[t], bj[t]);
                    }
                }
            }
        }
        // Keep-lower-half: min(ld[t], bd[31-t]) is bitonic; merge to ascending.
#pragma unroll
        for (int t = 0; t < 32; ++t) cswap(ld[t], lj[t], bd[31 - t], bj[31 - t]);
#pragma unroll
        for (int k = 16; k >= 1; k >>= 1) {
#pragma unroll
            for (int t = 0; t < 32; ++t) {
                if ((t & k) == 0) cswap(ld[t], lj[t], ld[t | k], lj[t | k]);
            }
        }
        thr = ld[KNN - 1];
        cnt = 0;
    };

    const int cbase = seg * SEGN;
    for (int c = 0; c < SEGN; c += 4) {
        const int cc = cbase + c;
        float4 fx = *(const float4*)(xb + cc);
        float4 fy = *(const float4*)(xb + N_PTS + cc);
        float4 fz = *(const float4*)(xb + 2 * N_PTS + cc);
#pragma unroll
        for (int q = 0; q < 4; ++q) {
            float xj = (q == 0) ? fx.x : (q == 1) ? fx.y : (q == 2) ? fx.z : fx.w;
            float yj = (q == 0) ? fy.x : (q == 1) ? fy.y : (q == 2) ? fy.z : fy.w;
            float zj = (q == 0) ? fz.x : (q == 1) ? fz.y : (q == 2) ? fz.z : fz.w;
            float sqj = sq_exact(xj, yj, zj);
            float d = dist_from_sq(xi, yi, zi, sqi, xj, yj, zj, sqj);
            int j = cc + q;
            // Gate d < thr (= current 20th entry) is EXACT: a rejected d == thr
            // candidate has larger j (ascending scan) => lex-rank > 20 forever.
            bool ok = (j != i) && (d < thr);
            if (ok) {
                stkd[cnt][tid] = d;
                stkj[cnt][tid] = (u32)j;
                ++cnt;
            }
        }
        // Entering a chunk every lane has cnt <= 20; +4 inserts max => <= 24. ✓
        if (__any(cnt >= SLOTS - 3)) merge_stack();
    }
    merge_stack();                            // drain

    // Publish this segment's exact top-20 (sorted by (d,j)).
#pragma unroll
    for (int t = 0; t < KNN; ++t) { stkd[t][tid] = ld[t]; stkj[t][tid] = lj[t]; }
    __syncthreads();

    // Final 4-way merge per query (threads 0..63, one query each).
    if (tid < 64) {
        const int q = tid;
        const int row = (b << 12) | ((blk & 63) << 6) | q;
        int p0 = 0, p1 = 0, p2 = 0, p3 = 0;
        float d0 = stkd[0][q],       d1 = stkd[0][q + 64];
        float d2 = stkd[0][q + 128], d3 = stkd[0][q + 192];
        u32   j0 = stkj[0][q],       j1 = stkj[0][q + 64];
        u32   j2 = stkj[0][q + 128], j3 = stkj[0][q + 192];
#pragma unroll
        for (int t = 0; t < KNN; ++t) {
            bool a = (d0 < d1) || ((d0 == d1) && (j0 < j1));
            float dA = a ? d0 : d1;  u32 jA = a ? j0 : j1;  int sA = a ? 0 : 1;
            bool bo = (d2 < d3) || ((d2 == d3) && (j2 < j3));
            float dB = bo ? d2 : d3; u32 jB = bo ? j2 : j3; int sB = bo ? 2 : 3;
            bool f = (dA < dB) || ((dA == dB) && (jA < jB));
            u32 jm = f ? jA : jB;    int sm = f ? sA : sB;
            knn_out[(size_t)row * KNN + t] = (u16)jm;
            if (sm == 0) {
                ++p0; bool okp = p0 < KNN;
                d0 = okp ? stkd[p0][q] : finf();       j0 = okp ? stkj[p0][q] : 0xFFFFFFFFu;
            } else if (sm == 1) {
                ++p1; bool okp = p1 < KNN;
                d1 = okp ? stkd[p1][q + 64] : finf();  j1 = okp ? stkj[p1][q + 64] : 0xFFFFFFFFu;
            } else if (sm == 2) {
                ++p2; bool okp = p2 < KNN;
                d2 = okp ? stkd[p2][q + 128] : finf(); j2 = okp ? stkj[p2][q + 128] : 0xFFFFFFFFu;
            } else {
                ++p3; bool okp = p3 < KNN;
                d3 = okp ? stkd[p3][q + 192] : finf(); j3 = okp ? stkj[p3][q + 192] : 0xFFFFFFFFu;
            }
        }
    }
}

// ---------------- Kernel 2: conv, coalesced tile (proven, ~130us) ----------------
__global__ __launch_bounds__(128) void conv_tile_kernel(
    const float* __restrict__ xloc,
    const float* __restrict__ xfeat,
    const float* __restrict__ Wrel,
    const float* __restrict__ brel,
    const float* __restrict__ Wroot,
    const u16* __restrict__ knn_in,
    float* __restrict__ out) {
    __shared__ float rowbuf[2][N_PTS];        // 32 KB
    const int tid = threadIdx.x;
    const int blk = blockIdx.x;               // b*32 + tile
    const int b   = blk >> 5;
    const int i   = ((blk & 31) << 7) | tid;  // point index within batch
    const float* xb = xloc + (size_t)b * 3 * N_PTS;
    const float* fb = xfeat + (size_t)b * 64 * N_PTS;

    // Output 0 passthrough (bit-exact, coalesced).
#pragma unroll
    for (int c = 0; c < 3; ++c)
        out[((size_t)b * 3 + c) * N_PTS + i] = xb[(size_t)c * N_PTS + i];

    // This thread's neighbor list -> registers (static indexing only).
    u32 kl[KNN / 2];
    const u32* kp = (const u32*)(knn_in + (size_t)((b << 12) | i) * KNN);
#pragma unroll
    for (int w = 0; w < KNN / 2; ++w) kl[w] = kp[w];
    int jj[KNN];
#pragma unroll
    for (int t = 0; t < KNN; ++t) jj[t] = (int)((kl[t >> 1] >> ((t & 1) * 16)) & 0xFFFFu);

    float rel[COUT], root[COUT];
#pragma unroll
    for (int c = 0; c < COUT; ++c) { rel[c] = 0.f; root[c] = 0.f; }

    auto stage = [&](int f) {
        const float* src = (f < 3) ? (xb + (size_t)f * N_PTS)
                                   : (fb + (size_t)(f - 3) * N_PTS);
        const float4* s4 = (const float4*)src;
        float4* d4 = (float4*)rowbuf[f & 1];
#pragma unroll
        for (int w = 0; w < 8; ++w) {
            int idx = w * 128 + tid;
            d4[idx] = s4[idx];
        }
    };

    stage(0);
    __syncthreads();

    for (int f = 0; f < FIN; ++f) {
        if (f + 1 < FIN) stage(f + 1);
        const float* cur = rowbuf[f & 1];
        float hf = cur[i];
        float af = 0.f;
#pragma unroll
        for (int t = 0; t < KNN; ++t) af += cur[jj[t]];   // ascending (dist,idx) order

        const float4* w4r = (const float4*)(Wrel + f * COUT);
        const float4* w4o = (const float4*)(Wroot + f * COUT);
#pragma unroll
        for (int c4 = 0; c4 < COUT / 4; ++c4) {
            float4 wr = w4r[c4], wo = w4o[c4];
            rel[c4 * 4 + 0] += af * wr.x;  root[c4 * 4 + 0] += hf * wo.x;
            rel[c4 * 4 + 1] += af * wr.y;  root[c4 * 4 + 1] += hf * wo.y;
            rel[c4 * 4 + 2] += af * wr.z;  root[c4 * 4 + 2] += hf * wo.z;
            rel[c4 * 4 + 3] += af * wr.w;  root[c4 * 4 + 3] += hf * wo.w;
        }
        __syncthreads();
    }

    const size_t ob = (size_t)NB * 3 * N_PTS + (size_t)b * COUT * N_PTS;
#pragma unroll
    for (int c = 0; c < COUT; ++c) {
        float acc = (rel[c] + brel[c]) + root[c];   // einsum + b_rel + einsum order
        out[ob + (size_t)c * N_PTS + i] = fmaxf(acc, 0.f);
    }
}

// ---------------- Fallback: proven round-7 monolithic kernel ----------------
__device__ __forceinline__ void insert3(float d, int c,
                                        float& v0, float& v1, float& v2,
                                        int& c0, int& c1, int& c2) {
    if (d < v2) {
        if (d < v1) {
            if (d < v0) { v2 = v1; c2 = c1; v1 = v0; c1 = c0; v0 = d; c0 = c; }
            else        { v2 = v1; c2 = c1; v1 = d;  c1 = c; }
        } else          { v2 = d;  c2 = c; }
    }
}

__global__ __launch_bounds__(64) void pcd_all(
    const float* __restrict__ xloc,
    const float* __restrict__ xfeat,
    const float* __restrict__ Wrel,
    const float* __restrict__ brel,
    const float* __restrict__ Wroot,
    float* __restrict__ out) {
    const int lane = threadIdx.x;
    const int row  = blockIdx.x;
    const int b    = row >> 12;
    const int i    = row & (N_PTS - 1);
    const float* xb = xloc + (size_t)b * 3 * N_PTS;

    if (lane < 3) {
        out[((size_t)b * 3 + lane) * N_PTS + i] = xb[(size_t)lane * N_PTS + i];
    }

    const float xi  = xb[i];
    const float yi  = xb[N_PTS + i];
    const float zi  = xb[2 * N_PTS + i];
    const float sqi = sq_exact(xi, yi, zi);

    float v0 = 1e30f, v1 = 1e30f, v2 = 1e30f;
    int   c0 = -1,    c1 = -1,    c2 = -1;

    for (int s = 0; s < 16; ++s) {
        int jb = s * 256 + lane * 4;
        float4 fx = *(const float4*)(xb + jb);
        float4 fy = *(const float4*)(xb + N_PTS + jb);
        float4 fz = *(const float4*)(xb + 2 * N_PTS + jb);
#pragma unroll
        for (int q = 0; q < 4; ++q) {
            float xj = (q == 0) ? fx.x : (q == 1) ? fx.y : (q == 2) ? fx.z : fx.w;
            float yj = (q == 0) ? fy.x : (q == 1) ? fy.y : (q == 2) ? fy.z : fy.w;
            float zj = (q == 0) ? fz.x : (q == 1) ? fz.y : (q == 2) ? fz.z : fz.w;
            int j = jb + q;
            float d = (j == i) ? 1e30f : dist_exact(xi, yi, zi, sqi, xj, yj, zj);
            insert3(d, s * 4 + q, v0, v1, v2, c0, c1, c2);
        }
    }

    u64 taken = 0;
    __shared__ int knn[KNN];

    for (int t = 0; t < KNN; ++t) {
        float bv = v0;
        int   bj = (c0 >= 0) ? (((c0 >> 2) << 8) + lane * 4 + (c0 & 3)) : (N_PTS - 1);
#pragma unroll
        for (int m = 1; m < 64; m <<= 1) {
            float ov = __shfl_xor(bv, m);
            int   oj = __shfl_xor(bj, m);
            if (ov < bv || (ov == bv && oj < bj)) { bv = ov; bj = oj; }
        }
        if (lane == 0) knn[t] = bj & (N_PTS - 1);
        int owner = (bj >> 2) & 63;
        if (lane == owner) {
            int cw = (((bj >> 8) << 2) | (bj & 3)) & 63;
            taken |= (1ull << cw);
            v0 = v1; c0 = c1; v1 = v2; c1 = c2; v2 = 1e30f; c2 = -1;
            if (v0 >= 1e30f) {
                v0 = v1 = v2 = 1e30f; c0 = c1 = c2 = -1;
                for (int s = 0; s < 16; ++s) {
                    int jb = s * 256 + lane * 4;
                    float4 fx = *(const float4*)(xb + jb);
                    float4 fy = *(const float4*)(xb + N_PTS + jb);
                    float4 fz = *(const float4*)(xb + 2 * N_PTS + jb);
#pragma unroll
                    for (int q = 0; q < 4; ++q) {
                        int cc = s * 4 + q;
                        if ((taken >> cc) & 1ull) continue;
                        int j = jb + q;
                        if (j == i) continue;
                        float xj = (q == 0) ? fx.x : (q == 1) ? fx.y : (q == 2) ? fx.z : fx.w;
                        float yj = (q == 0) ? fy.x : (q == 1) ? fy.y : (q == 2) ? fy.z : fy.w;
                        float zj = (q == 0) ? fz.x : (q == 1) ? fz.y : (q == 2) ? fz.z : fz.w;
                        float d = dist_exact(xi, yi, zi, sqi, xj, yj, zj);
                        insert3(d, cc, v0, v1, v2, c0, c1, c2);
                    }
                }
            }
        }
    }

    __syncthreads();

    __shared__ float aggf[FIN + 1];
    __shared__ float hif[FIN + 1];

    const float* xfb = xfeat + ((size_t)b * 64 + lane) * N_PTS;
    const float* xlb = xb + (size_t)(lane < 3 ? lane : 0) * N_PTS;
    float af = 0.f, al = 0.f;
    for (int t = 0; t < KNN; ++t) {
        int j = knn[t];
        af += xfb[j];
        if (lane < 3) al += xlb[j];
    }
    aggf[3 + lane] = af;
    hif[3 + lane]  = xfb[i];
    if (lane < 3) { aggf[lane] = al; hif[lane] = xlb[i]; }
    __syncthreads();

    float acc_rel = 0.f, acc_root = 0.f;
    for (int f = 0; f < FIN; ++f) {
        acc_rel  += aggf[f] * Wrel[f * COUT + lane];
        acc_root += hif[f]  * Wroot[f * COUT + lane];
    }
    float acc = (acc_rel + brel[lane]) + acc_root;
    acc = fmaxf(acc, 0.0f);
    out[(size_t)NB * 3 * N_PTS + ((((size_t)b << 6) | lane) << 12) + i] = acc;
}

extern "C" void kernel_launch(void* const* d_in, const int* in_sizes, int n_in,
                              void* d_out, int out_size, void* d_ws, size_t ws_size,
                              hipStream_t stream) {
    const float* xloc  = nullptr;
    const float* xfeat = nullptr;
    const float* Wrel  = nullptr;
    const float* brel  = nullptr;
    const float* Wroot = nullptr;
    for (int idx = 0; idx < n_in; ++idx) {
        const long long s = in_sizes[idx];
        const float* p = (const float*)d_in[idx];
        if (s == 98304LL || s == 393216LL)          { xloc = p; }
        else if (s == 2097152LL || s == 8388608LL)  { xfeat = p; }
        else if (s == 4288LL || s == 17152LL)       { if (!Wrel) Wrel = p; else Wroot = p; }
        else if (s == 64LL || s == 256LL)           { brel = p; }
    }
    if (!xloc || !xfeat || !Wrel || !brel || !Wroot) {
        xloc  = (const float*)d_in[0];
        xfeat = (const float*)d_in[1];
        Wrel  = (const float*)d_in[2];
        brel  = (const float*)d_in[3];
        Wroot = (const float*)d_in[4];
    }

    const size_t KNN_BYTES = (size_t)NB * N_PTS * KNN * sizeof(u16);  // 1.31 MB
    if (d_ws != nullptr && ws_size >= KNN_BYTES) {
        u16* knn_ws = (u16*)d_ws;
        knn_seg_kernel<<<dim3(NB * 64), dim3(256), 0, stream>>>(xloc, knn_ws);
        conv_tile_kernel<<<dim3(NB * 32), dim3(128), 0, stream>>>(
            xloc, xfeat, Wrel, brel, Wroot, knn_ws, (float*)d_out);
    } else {
        pcd_all<<<dim3(NB * N_PTS), dim3(64), 0, stream>>>(
            xloc, xfeat, Wrel, brel, Wroot, (float*)d_out);
    }
}

// Round 14
// 379.614 us; speedup vs baseline: 1.2864x; 1.2864x over previous
//
#include <hip/hip_runtime.h>

#define N_PTS 4096
#define NB    8
#define KNN   20
#define FIN   67
#define COUT  64
#define SEG   8
#define SEGN  (N_PTS / SEG)   // 512 candidates per segment-thread
#define SLOTS 16              // LDS stack slots per thread
#define QPB   32              // queries per block (x SEG segments = 256 threads)

typedef unsigned short u16;
typedef unsigned int   u32;
typedef unsigned long long u64;

__device__ __forceinline__ float finf() { return __uint_as_float(0x7f800000u); }

// Order-preserving f32 -> u32 map (total order, matches IEEE < on non-NaN).
__device__ __forceinline__ u32 fmap(float f) {
    u32 b = __float_as_uint(f);
    return b ^ ((u32)((int)b >> 31) | 0x80000000u);
}

// sq = (x*x + y*y) + z*z, all f32, no FMA (matches np op order).
__device__ __forceinline__ float sq_exact(float x, float y, float z) {
#pragma clang fp contract(off)
    float s = (x * x + y * y) + z * z;
    return s;
}

// dist = (sq_i - 2*dot) + sq_j, dot = (x_i*x_j + y_i*y_j) + z_i*z_j, no FMA.
__device__ __forceinline__ float dist_from_sq(float xi, float yi, float zi, float sqi,
                                              float xj, float yj, float zj, float sqj) {
#pragma clang fp contract(off)
    float d0 = xi * xj, d1 = yi * yj, d2 = zi * zj;
    float dot = (d0 + d1) + d2;
    float d = (sqi - 2.0f * dot) + sqj;
    return d;
}

__device__ __forceinline__ float dist_exact(float xi, float yi, float zi, float sqi,
                                            float xj, float yj, float zj) {
#pragma clang fp contract(off)
    float d0 = xi * xj, d1 = yi * yj, d2 = zi * zj;
    float dot = (d0 + d1) + d2;
    float sqj = (xj * xj + yj * yj) + zj * zj;
    float d = (sqi - 2.0f * dot) + sqj;
    return d;
}

// u64 key = fmap(d) << 12 | j  — plain u64 < is EXACT (d, j) lex order.
__device__ __forceinline__ void cswap64(u64& a, u64& b) {
    bool sw = b < a;
    u64 na = sw ? b : a, nb = sw ? a : b;
    a = na; b = nb;
}

// ---------------- Kernel 1: kNN, (query, segment) per thread ----------------
// Block = 256 threads = 32 queries x 8 segments of 512 candidates.
// 1024 blocks -> 4 blocks/CU, 16 waves/CU (round-13 limiter was 2 waves/SIMD).
// Exact top-20 per segment (u64-key threshold gate + SoA LDS stack + static
// bitonic merges), then an exact 8-way tournament merge per query.
__global__ __launch_bounds__(256) void knn_seg8_kernel(
    const float* __restrict__ xloc, u16* __restrict__ knn_out) {
    __shared__ u64 stk[SLOTS][256];           // 32 KB, bank-free SoA
    __shared__ u64 ext[KNN - SLOTS][256];     // 8 KB  (publish slots 16..19)
    const int tid  = threadIdx.x;
    const int q    = tid & (QPB - 1);         // query within tile
    const int seg  = tid >> 5;                // candidate segment
    const int blk  = blockIdx.x;              // b*128 + qtile
    const int b    = blk >> 7;
    const int i    = ((blk & 127) << 5) | q;
    const float* xb = xloc + (size_t)b * 3 * N_PTS;

    const float xi = xb[i], yi = xb[N_PTS + i], zi = xb[2 * N_PTS + i];
    const float sqi = sq_exact(xi, yi, zi);

    u64 ld[32];
#pragma unroll
    for (int t = 0; t < 32; ++t) ld[t] = ~0ull;
    u64 thr = ~0ull;
    int cnt = 0;

    auto merge_stack = [&]() {
        u64 bd[SLOTS];
#pragma unroll
        for (int t = 0; t < SLOTS; ++t) bd[t] = (t < cnt) ? stk[t][tid] : ~0ull;
        // Bitonic sort-16 ascending.
#pragma unroll
        for (int k = 2; k <= SLOTS; k <<= 1) {
#pragma unroll
            for (int s = k >> 1; s > 0; s >>= 1) {
#pragma unroll
                for (int t = 0; t < SLOTS; ++t) {
                    int l = t ^ s;
                    if (l > t) {
                        if ((t & k) == 0) cswap64(bd[t], bd[l]);
                        else              cswap64(bd[l], bd[t]);
                    }
                }
            }
        }
        // Keep-lower-half vs padded-to-32 stack (pads are +inf -> no-op swaps),
        // then bitonic-merge-32. Identical network to the proven 32+32 case.
#pragma unroll
        for (int t = 0; t < SLOTS; ++t) cswap64(ld[31 - t], bd[t]);
#pragma unroll
        for (int k = 16; k >= 1; k >>= 1) {
#pragma unroll
            for (int t = 0; t < 32; ++t) {
                if ((t & k) == 0) cswap64(ld[t], ld[t | k]);
            }
        }
        thr = ld[KNN - 1];
        cnt = 0;
    };

    const int cbase = seg * SEGN;
    for (int c = 0; c < SEGN; c += 4) {
        const int cc = cbase + c;
        float4 fx = *(const float4*)(xb + cc);
        float4 fy = *(const float4*)(xb + N_PTS + cc);
        float4 fz = *(const float4*)(xb + 2 * N_PTS + cc);
#pragma unroll
        for (int qq = 0; qq < 4; ++qq) {
            float xj = (qq == 0) ? fx.x : (qq == 1) ? fx.y : (qq == 2) ? fx.z : fx.w;
            float yj = (qq == 0) ? fy.x : (qq == 1) ? fy.y : (qq == 2) ? fy.z : fy.w;
            float zj = (qq == 0) ? fz.x : (qq == 1) ? fz.y : (qq == 2) ? fz.z : fz.w;
            float sqj = sq_exact(xj, yj, zj);
            float d = dist_from_sq(xi, yi, zi, sqi, xj, yj, zj, sqj);
            int j = cc + qq;
            u64 key = ((u64)fmap(d) << 12) | (u32)j;
            // key < thr is the exact (d, j)-lex gate vs the current 20th entry.
            bool ok = (j != i) && (key < thr);
            if (ok) {
                stk[cnt][tid] = key;
                ++cnt;
            }
        }
        // Entering a chunk all lanes have cnt <= 12; +4 max => <= 16. ✓
        if (__any(cnt >= SLOTS - 3)) merge_stack();
    }
    merge_stack();                            // drain

    // Publish this segment's exact sorted top-20.
#pragma unroll
    for (int t = 0; t < SLOTS; ++t) stk[t][tid] = ld[t];
#pragma unroll
    for (int t = SLOTS; t < KNN; ++t) ext[t - SLOTS][tid] = ld[t];
    __syncthreads();

    // Exact 8-way tournament merge per query (threads 0..31).
    if (tid < QPB) {
        const int col0 = tid;                 // stream s lives at column tid + 32*s
        const int row  = (b << 12) | ((blk & 127) << 5) | tid;
        int  pp[SEG];
        u64  kk[SEG];
#pragma unroll
        for (int s = 0; s < SEG; ++s) { pp[s] = 0; kk[s] = stk[0][col0 + 32 * s]; }
#pragma unroll
        for (int t = 0; t < KNN; ++t) {
            u64 best = kk[0]; int sm = 0;
#pragma unroll
            for (int s = 1; s < SEG; ++s)
                if (kk[s] < best) { best = kk[s]; sm = s; }
            knn_out[(size_t)row * KNN + t] = (u16)(best & 0xFFFu);
#pragma unroll
            for (int s = 0; s < SEG; ++s) {
                if (s == sm) {
                    int p = ++pp[s];
                    int col = col0 + 32 * s;
                    kk[s] = (p < KNN) ? ((p < SLOTS) ? stk[p][col] : ext[p - SLOTS][col])
                                      : ~0ull;
                }
            }
        }
    }
}

// ---------------- Kernel 2: conv, 32-pt x 4 channel-quarter tiles ----------------
// 1024 blocks x 128 threads -> 4 blocks/CU, 8 waves/CU (round-13 conv was
// 1 block/CU). thread = (point p, channel quarter qtr); all writes coalesced.
__global__ __launch_bounds__(128) void conv_q_kernel(
    const float* __restrict__ xloc,
    const float* __restrict__ xfeat,
    const float* __restrict__ Wrel,
    const float* __restrict__ brel,
    const float* __restrict__ Wroot,
    const u16* __restrict__ knn_in,
    float* __restrict__ out) {
    __shared__ float rowbuf[2][N_PTS];        // 32 KB
    const int tid = threadIdx.x;
    const int p   = tid & 31;                 // point within tile
    const int qtr = tid >> 5;                 // channel quarter (16 ch)
    const int blk = blockIdx.x;               // b*128 + tile
    const int b   = blk >> 7;
    const int i   = ((blk & 127) << 5) | p;   // point index within batch
    const float* xb = xloc + (size_t)b * 3 * N_PTS;
    const float* fb = xfeat + (size_t)b * 64 * N_PTS;

    // Output 0 passthrough (bit-exact, coalesced) — one quarter only.
    if (qtr == 0) {
#pragma unroll
        for (int c = 0; c < 3; ++c)
            out[((size_t)b * 3 + c) * N_PTS + i] = xb[(size_t)c * N_PTS + i];
    }

    // Neighbor list -> registers (static indexing only).
    u32 kl[KNN / 2];
    const u32* kp = (const u32*)(knn_in + (size_t)((b << 12) | i) * KNN);
#pragma unroll
    for (int w = 0; w < KNN / 2; ++w) kl[w] = kp[w];
    int jj[KNN];
#pragma unroll
    for (int t = 0; t < KNN; ++t) jj[t] = (int)((kl[t >> 1] >> ((t & 1) * 16)) & 0xFFFFu);

    float rel[16], root[16];
#pragma unroll
    for (int c = 0; c < 16; ++c) { rel[c] = 0.f; root[c] = 0.f; }

    auto stage = [&](int f) {
        const float* src = (f < 3) ? (xb + (size_t)f * N_PTS)
                                   : (fb + (size_t)(f - 3) * N_PTS);
        const float4* s4 = (const float4*)src;
        float4* d4 = (float4*)rowbuf[f & 1];
#pragma unroll
        for (int w = 0; w < 8; ++w) {
            int idx = w * 128 + tid;
            d4[idx] = s4[idx];
        }
    };

    stage(0);
    __syncthreads();

    for (int f = 0; f < FIN; ++f) {
        if (f + 1 < FIN) stage(f + 1);
        const float* cur = rowbuf[f & 1];
        float hf = cur[i];
        float af = 0.f;
#pragma unroll
        for (int t = 0; t < KNN; ++t) af += cur[jj[t]];   // ascending (dist,idx) order

        const float4* w4r = (const float4*)(Wrel + f * COUT + qtr * 16);
        const float4* w4o = (const float4*)(Wroot + f * COUT + qtr * 16);
#pragma unroll
        for (int c4 = 0; c4 < 4; ++c4) {
            float4 wr = w4r[c4], wo = w4o[c4];
            rel[c4 * 4 + 0] += af * wr.x;  root[c4 * 4 + 0] += hf * wo.x;
            rel[c4 * 4 + 1] += af * wr.y;  root[c4 * 4 + 1] += hf * wo.y;
            rel[c4 * 4 + 2] += af * wr.z;  root[c4 * 4 + 2] += hf * wo.z;
            rel[c4 * 4 + 3] += af * wr.w;  root[c4 * 4 + 3] += hf * wo.w;
        }
        __syncthreads();
    }

    const size_t ob = (size_t)NB * 3 * N_PTS + (size_t)b * COUT * N_PTS;
#pragma unroll
    for (int c = 0; c < 16; ++c) {
        int cc = qtr * 16 + c;
        float acc = (rel[c] + brel[cc]) + root[c];  // einsum + b_rel + einsum order
        out[ob + (size_t)cc * N_PTS + i] = fmaxf(acc, 0.f);
    }
}

// ---------------- Fallback: proven round-7 monolithic kernel ----------------
__device__ __forceinline__ void insert3(float d, int c,
                                        float& v0, float& v1, float& v2,
                                        int& c0, int& c1, int& c2) {
    if (d < v2) {
        if (d < v1) {
            if (d < v0) { v2 = v1; c2 = c1; v1 = v0; c1 = c0; v0 = d; c0 = c; }
            else        { v2 = v1; c2 = c1; v1 = d;  c1 = c; }
        } else          { v2 = d;  c2 = c; }
    }
}

__global__ __launch_bounds__(64) void pcd_all(
    const float* __restrict__ xloc,
    const float* __restrict__ xfeat,
    const float* __restrict__ Wrel,
    const float* __restrict__ brel,
    const float* __restrict__ Wroot,
    float* __restrict__ out) {
    const int lane = threadIdx.x;
    const int row  = blockIdx.x;
    const int b    = row >> 12;
    const int i    = row & (N_PTS - 1);
    const float* xb = xloc + (size_t)b * 3 * N_PTS;

    if (lane < 3) {
        out[((size_t)b * 3 + lane) * N_PTS + i] = xb[(size_t)lane * N_PTS + i];
    }

    const float xi  = xb[i];
    const float yi  = xb[N_PTS + i];
    const float zi  = xb[2 * N_PTS + i];
    const float sqi = sq_exact(xi, yi, zi);

    float v0 = 1e30f, v1 = 1e30f, v2 = 1e30f;
    int   c0 = -1,    c1 = -1,    c2 = -1;

    for (int s = 0; s < 16; ++s) {
        int jb = s * 256 + lane * 4;
        float4 fx = *(const float4*)(xb + jb);
        float4 fy = *(const float4*)(xb + N_PTS + jb);
        float4 fz = *(const float4*)(xb + 2 * N_PTS + jb);
#pragma unroll
        for (int q = 0; q < 4; ++q) {
            float xj = (q == 0) ? fx.x : (q == 1) ? fx.y : (q == 2) ? fx.z : fx.w;
            float yj = (q == 0) ? fy.x : (q == 1) ? fy.y : (q == 2) ? fy.z : fy.w;
            float zj = (q == 0) ? fz.x : (q == 1) ? fz.y : (q == 2) ? fz.z : fz.w;
            int j = jb + q;
            float d = (j == i) ? 1e30f : dist_exact(xi, yi, zi, sqi, xj, yj, zj);
            insert3(d, s * 4 + q, v0, v1, v2, c0, c1, c2);
        }
    }

    u64 taken = 0;
    __shared__ int knn[KNN];

    for (int t = 0; t < KNN; ++t) {
        float bv = v0;
        int   bj = (c0 >= 0) ? (((c0 >> 2) << 8) + lane * 4 + (c0 & 3)) : (N_PTS - 1);
#pragma unroll
        for (int m = 1; m < 64; m <<= 1) {
            float ov = __shfl_xor(bv, m);
            int   oj = __shfl_xor(bj, m);
            if (ov < bv || (ov == bv && oj < bj)) { bv = ov; bj = oj; }
        }
        if (lane == 0) knn[t] = bj & (N_PTS - 1);
        int owner = (bj >> 2) & 63;
        if (lane == owner) {
            int cw = (((bj >> 8) << 2) | (bj & 3)) & 63;
            taken |= (1ull << cw);
            v0 = v1; c0 = c1; v1 = v2; c1 = c2; v2 = 1e30f; c2 = -1;
            if (v0 >= 1e30f) {
                v0 = v1 = v2 = 1e30f; c0 = c1 = c2 = -1;
                for (int s = 0; s < 16; ++s) {
                    int jb = s * 256 + lane * 4;
                    float4 fx = *(const float4*)(xb + jb);
                    float4 fy = *(const float4*)(xb + N_PTS + jb);
                    float4 fz = *(const float4*)(xb + 2 * N_PTS + jb);
#pragma unroll
                    for (int q = 0; q < 4; ++q) {
                        int cc = s * 4 + q;
                        if ((taken >> cc) & 1ull) continue;
                        int j = jb + q;
                        if (j == i) continue;
                        float xj = (q == 0) ? fx.x : (q == 1) ? fx.y : (q == 2) ? fx.z : fx.w;
                        float yj = (q == 0) ? fy.x : (q == 1) ? fy.y : (q == 2) ? fy.z : fy.w;
                        float zj = (q == 0) ? fz.x : (q == 1) ? fz.y : (q == 2) ? fz.z : fz.w;
                        float d = dist_exact(xi, yi, zi, sqi, xj, yj, zj);
                        insert3(d, cc, v0, v1, v2, c0, c1, c2);
                    }
                }
            }
        }
    }

    __syncthreads();

    __shared__ float aggf[FIN + 1];
    __shared__ float hif[FIN + 1];

    const float* xfb = xfeat + ((size_t)b * 64 + lane) * N_PTS;
    const float* xlb = xb + (size_t)(lane < 3 ? lane : 0) * N_PTS;
    float af = 0.f, al = 0.f;
    for (int t = 0; t < KNN; ++t) {
        int j = knn[t];
        af += xfb[j];
        if (lane < 3) al += xlb[j];
    }
    aggf[3 + lane] = af;
    hif[3 + lane]  = xfb[i];
    if (lane < 3) { aggf[lane] = al; hif[lane] = xlb[i]; }
    __syncthreads();

    float acc_rel = 0.f, acc_root = 0.f;
    for (int f = 0; f < FIN; ++f) {
        acc_rel  += aggf[f] * Wrel[f * COUT + lane];
        acc_root += hif[f]  * Wroot[f * COUT + lane];
    }
    float acc = (acc_rel + brel[lane]) + acc_root;
    acc = fmaxf(acc, 0.0f);
    out[(size_t)NB * 3 * N_PTS + ((((size_t)b << 6) | lane) << 12) + i] = acc;
}

extern "C" void kernel_launch(void* const* d_in, const int* in_sizes, int n_in,
                              void* d_out, int out_size, void* d_ws, size_t ws_size,
                              hipStream_t stream) {
    const float* xloc  = nullptr;
    const float* xfeat = nullptr;
    const float* Wrel  = nullptr;
    const float* brel  = nullptr;
    const float* Wroot = nullptr;
    for (int idx = 0; idx < n_in; ++idx) {
        const long long s = in_sizes[idx];
        const float* p = (const float*)d_in[idx];
        if (s == 98304LL || s == 393216LL)          { xloc = p; }
        else if (s == 2097152LL || s == 8388608LL)  { xfeat = p; }
        else if (s == 4288LL || s == 17152LL)       { if (!Wrel) Wrel = p; else Wroot = p; }
        else if (s == 64LL || s == 256LL)           { brel = p; }
    }
    if (!xloc || !xfeat || !Wrel || !brel || !Wroot) {
        xloc  = (const float*)d_in[0];
        xfeat = (const float*)d_in[1];
        Wrel  = (const float*)d_in[2];
        brel  = (const float*)d_in[3];
        Wroot = (const float*)d_in[4];
    }

    const size_t KNN_BYTES = (size_t)NB * N_PTS * KNN * sizeof(u16);  // 1.31 MB
    if (d_ws != nullptr && ws_size >= KNN_BYTES) {
        u16* knn_ws = (u16*)d_ws;
        knn_seg8_kernel<<<dim3(NB * 128), dim3(256), 0, stream>>>(xloc, knn_ws);
        conv_q_kernel<<<dim3(NB * 128), dim3(128), 0, stream>>>(
            xloc, xfeat, Wrel, brel, Wroot, knn_ws, (float*)d_out);
    } else {
        pcd_all<<<dim3(NB * N_PTS), dim3(64), 0, stream>>>(
            xloc, xfeat, Wrel, brel, Wroot, (float*)d_out);
    }
}

// Round 15
// 354.341 us; speedup vs baseline: 1.3782x; 1.0713x over previous
//
#include <hip/hip_runtime.h>

#define N_PTS 4096
#define NB    8
#define KNN   20
#define FIN   67
#define COUT  64
#define SEG   8
#define SEGN  (N_PTS / SEG)   // 512 candidates per segment-thread
#define SLOTS 16              // LDS stack slots per thread
#define QPB   32              // queries per block (x SEG segments = 256 threads)

typedef unsigned short u16;
typedef unsigned int   u32;
typedef unsigned long long u64;

// ws layout (bytes)
#define KNN_BYTES 1310720u                      // 8*4096*20*2
#define FT_OFF    1310720u                      // ft[b][n][64] f32 = 8388608
#define PK_OFF    (FT_OFF + 8388608u)           // pack[b][n] float4 = 524288
#define WS_NEED   (PK_OFF + 524288u)            // 10223616

__device__ __forceinline__ float finf() { return __uint_as_float(0x7f800000u); }

// Order-preserving f32 -> u32 map (total order, matches IEEE < on non-NaN).
__device__ __forceinline__ u32 fmap(float f) {
    u32 b = __float_as_uint(f);
    return b ^ ((u32)((int)b >> 31) | 0x80000000u);
}

// sq = (x*x + y*y) + z*z, all f32, no FMA (matches np op order).
__device__ __forceinline__ float sq_exact(float x, float y, float z) {
#pragma clang fp contract(off)
    float s = (x * x + y * y) + z * z;
    return s;
}

// dist = (sq_i - 2*dot) + sq_j, dot = (x_i*x_j + y_i*y_j) + z_i*z_j, no FMA.
__device__ __forceinline__ float dist_from_sq(float xi, float yi, float zi, float sqi,
                                              float xj, float yj, float zj, float sqj) {
#pragma clang fp contract(off)
    float d0 = xi * xj, d1 = yi * yj, d2 = zi * zj;
    float dot = (d0 + d1) + d2;
    float d = (sqi - 2.0f * dot) + sqj;
    return d;
}

__device__ __forceinline__ float dist_exact(float xi, float yi, float zi, float sqi,
                                            float xj, float yj, float zj) {
#pragma clang fp contract(off)
    float d0 = xi * xj, d1 = yi * yj, d2 = zi * zj;
    float dot = (d0 + d1) + d2;
    float sqj = (xj * xj + yj * yj) + zj * zj;
    float d = (sqi - 2.0f * dot) + sqj;
    return d;
}

// u64 key = fmap(d) << 12 | j  — plain u64 < is EXACT (d, j) lex order.
__device__ __forceinline__ void cswap64(u64& a, u64& b) {
    bool sw = b < a;
    u64 na = sw ? b : a, nb = sw ? a : b;
    a = na; b = nb;
}

// ---------------- Kernel 0: transpose/pack + out0 passthrough ----------------
// 512 blocks x 256 threads; block = (b, 64-point tile).
//  - out0[0:98304] = bit-exact f32 copy of x_loc (float4, coalesced)
//  - pack[b][n] = {x, y, z, sq_exact(x,y,z)}  (sq bit-identical to inline form)
//  - ft[b][n][64] = x_feat[b][:, n]  (64x64 LDS-tiled transpose)
__global__ __launch_bounds__(256) void transpose_kernel(
    const float* __restrict__ xloc, const float* __restrict__ xfeat,
    float* __restrict__ ft, float4* __restrict__ pack, float* __restrict__ out) {
    __shared__ float tile[64][65];
    const int tid = threadIdx.x;
    const int blk = blockIdx.x;               // b*64 + ntile
    const int b   = blk >> 6;
    const int n0  = (blk & 63) << 6;
    const int tx  = tid & 63, w = tid >> 6;

    if (tid < 48) {
        int idx4 = blk * 48 + tid;            // 512*48 = 24576 float4 = 98304 f32
        ((float4*)out)[idx4] = ((const float4*)xloc)[idx4];
    }
    if (w == 0) {
        float x = xloc[((size_t)b * 3 + 0) * N_PTS + n0 + tx];
        float y = xloc[((size_t)b * 3 + 1) * N_PTS + n0 + tx];
        float z = xloc[((size_t)b * 3 + 2) * N_PTS + n0 + tx];
        pack[((size_t)b << 12) + n0 + tx] = make_float4(x, y, z, sq_exact(x, y, z));
    }
#pragma unroll
    for (int k = 0; k < 16; ++k) {
        int c = w * 16 + k;
        tile[tx][c] = xfeat[((size_t)(b << 6) + c) * N_PTS + n0 + tx];
    }
    __syncthreads();
#pragma unroll
    for (int k = 0; k < 16; ++k) {
        int n = w * 16 + k;
        ft[(((size_t)(b << 12)) + n0 + n) * 64 + tx] = tile[n][tx];
    }
}

// ---------------- Kernel 1: kNN from pack (r14-proven structure) ----------------
// Block = 256 threads = 32 queries x 8 segments of 512 candidates. Per-candidate
// work: 1 float4 load + dist_from_sq (sq precomputed) vs r14's 3 loads + sq.
__global__ __launch_bounds__(256) void knn_pack_kernel(
    const float4* __restrict__ pack, u16* __restrict__ knn_out) {
    __shared__ u64 stk[SLOTS][256];           // 32 KB, bank-free SoA
    __shared__ u64 ext[KNN - SLOTS][256];     // 8 KB  (publish slots 16..19)
    const int tid  = threadIdx.x;
    const int q    = tid & (QPB - 1);
    const int seg  = tid >> 5;
    const int blk  = blockIdx.x;              // b*128 + qtile
    const int b    = blk >> 7;
    const int i    = ((blk & 127) << 5) | q;
    const float4* pb = pack + ((size_t)b << 12);

    const float4 qp = pb[i];
    const float xi = qp.x, yi = qp.y, zi = qp.z, sqi = qp.w;

    u64 ld[32];
#pragma unroll
    for (int t = 0; t < 32; ++t) ld[t] = ~0ull;
    u64 thr = ~0ull;
    int cnt = 0;

    auto merge_stack = [&]() {
        u64 bd[SLOTS];
#pragma unroll
        for (int t = 0; t < SLOTS; ++t) bd[t] = (t < cnt) ? stk[t][tid] : ~0ull;
#pragma unroll
        for (int k = 2; k <= SLOTS; k <<= 1) {
#pragma unroll
            for (int s = k >> 1; s > 0; s >>= 1) {
#pragma unroll
                for (int t = 0; t < SLOTS; ++t) {
                    int l = t ^ s;
                    if (l > t) {
                        if ((t & k) == 0) cswap64(bd[t], bd[l]);
                        else              cswap64(bd[l], bd[t]);
                    }
                }
            }
        }
#pragma unroll
        for (int t = 0; t < SLOTS; ++t) cswap64(ld[31 - t], bd[t]);
#pragma unroll
        for (int k = 16; k >= 1; k >>= 1) {
#pragma unroll
            for (int t = 0; t < 32; ++t) {
                if ((t & k) == 0) cswap64(ld[t], ld[t | k]);
            }
        }
        thr = ld[KNN - 1];
        cnt = 0;
    };

    auto process = [&](const float4& pk, int j) {
        float d = dist_from_sq(xi, yi, zi, sqi, pk.x, pk.y, pk.z, pk.w);
        u64 key = ((u64)fmap(d) << 12) | (u32)j;
        bool ok = (j != i) && (key < thr);
        if (ok) { stk[cnt][tid] = key; ++cnt; }
    };

    const int cbase = seg * SEGN;
    for (int c = 0; c < SEGN; c += 4) {
        const int cc = cbase + c;
        float4 p0 = pb[cc + 0], p1 = pb[cc + 1], p2 = pb[cc + 2], p3 = pb[cc + 3];
        process(p0, cc + 0);
        process(p1, cc + 1);
        process(p2, cc + 2);
        process(p3, cc + 3);
        // Entering a chunk all lanes have cnt <= 12; +4 max => <= 16. ✓
        if (__any(cnt >= SLOTS - 3)) merge_stack();
    }
    merge_stack();                            // drain

#pragma unroll
    for (int t = 0; t < SLOTS; ++t) stk[t][tid] = ld[t];
#pragma unroll
    for (int t = SLOTS; t < KNN; ++t) ext[t - SLOTS][tid] = ld[t];
    __syncthreads();

    if (tid < QPB) {
        const int col0 = tid;
        const int row  = (b << 12) | ((blk & 127) << 5) | tid;
        int  pp[SEG];
        u64  kk[SEG];
#pragma unroll
        for (int s = 0; s < SEG; ++s) { pp[s] = 0; kk[s] = stk[0][col0 + 32 * s]; }
#pragma unroll
        for (int t = 0; t < KNN; ++t) {
            u64 best = kk[0]; int sm = 0;
#pragma unroll
            for (int s = 1; s < SEG; ++s)
                if (kk[s] < best) { best = kk[s]; sm = s; }
            knn_out[(size_t)row * KNN + t] = (u16)(best & 0xFFFu);
#pragma unroll
            for (int s = 0; s < SEG; ++s) {
                if (s == sm) {
                    int p = ++pp[s];
                    int col = col0 + 32 * s;
                    kk[s] = (p < KNN) ? ((p < SLOTS) ? stk[p][col] : ext[p - SLOTS][col])
                                      : ~0ull;
                }
            }
        }
    }
}

// ---------------- Kernel 2: conv via coalesced ft-row gathers ----------------
// 1024 blocks x 128 threads; block = (b, 32-point tile).
// Phase 1: wave w gathers points w*16..w*16+15 — lane = channel; neighbor row
//   read ft[j*64+lane] is ONE 256B coalesced L2 transaction (no LDS conflicts,
//   no per-row barriers — the round-14 regression). agg/h -> LDS [32][69]
//   (odd stride -> conflict-free).
// Phase 2: thread = (channel-quarter, point); scalar-ish W reads; coalesced out.
__global__ __launch_bounds__(128) void conv_g_kernel(
    const float* __restrict__ Wrel,
    const float* __restrict__ brel,
    const float* __restrict__ Wroot,
    const u16* __restrict__ knn_in,
    const float* __restrict__ ft,
    const float4* __restrict__ pack,
    float* __restrict__ out) {
    __shared__ float aggf[32][69];
    __shared__ float hif[32][69];
    const int tid = threadIdx.x;
    const int blk = blockIdx.x;               // b*128 + tile
    const int b   = blk >> 7;
    const int i0  = (blk & 127) << 5;
    const int lane = tid & 63, w = tid >> 6;
    const float* ftb = ft + (((size_t)b << 12)) * 64;
    const float* pkb = (const float*)(pack + ((size_t)b << 12));

    for (int pp = 0; pp < 16; ++pp) {
        int p = w * 16 + pp;
        int i = i0 + p;
        const u16* kl = knn_in + (size_t)((b << 12) | i) * KNN;
        float af = 0.f, al = 0.f;
        float hfv = ftb[(size_t)i * 64 + lane];
        float hlv = (lane < 3) ? pkb[(size_t)i * 4 + lane] : 0.f;
        for (int t = 0; t < KNN; ++t) {       // ascending (dist, idx) order
            int j = kl[t];
            af += ftb[(size_t)j * 64 + lane];
            if (lane < 3) al += pkb[(size_t)j * 4 + lane];
        }
        aggf[p][3 + lane] = af;               // f = 3..66
        hif[p][3 + lane]  = hfv;
        if (lane < 3) { aggf[p][lane] = al; hif[p][lane] = hlv; }
    }
    __syncthreads();

    const int p2  = tid & 31, qtr = tid >> 5;
    const int i2  = i0 + p2;
    float rel[16], root[16];
#pragma unroll
    for (int c = 0; c < 16; ++c) { rel[c] = 0.f; root[c] = 0.f; }
    for (int f = 0; f < FIN; ++f) {
        float a = aggf[p2][f];
        float h = hif[p2][f];
        const float4* w4r = (const float4*)(Wrel + f * COUT + qtr * 16);
        const float4* w4o = (const float4*)(Wroot + f * COUT + qtr * 16);
#pragma unroll
        for (int c4 = 0; c4 < 4; ++c4) {
            float4 wr = w4r[c4], wo = w4o[c4];
            rel[c4 * 4 + 0] += a * wr.x;  root[c4 * 4 + 0] += h * wo.x;
            rel[c4 * 4 + 1] += a * wr.y;  root[c4 * 4 + 1] += h * wo.y;
            rel[c4 * 4 + 2] += a * wr.z;  root[c4 * 4 + 2] += h * wo.z;
            rel[c4 * 4 + 3] += a * wr.w;  root[c4 * 4 + 3] += h * wo.w;
        }
    }
    const size_t ob = (size_t)NB * 3 * N_PTS + (size_t)b * COUT * N_PTS;
#pragma unroll
    for (int c = 0; c < 16; ++c) {
        int cc = qtr * 16 + c;
        float acc = (rel[c] + brel[cc]) + root[c];  // einsum + b_rel + einsum order
        out[ob + (size_t)cc * N_PTS + i2] = fmaxf(acc, 0.f);
    }
}

// ================= r14 fallback path (proven, 379us) =================
__global__ __launch_bounds__(256) void knn_seg8_kernel(
    const float* __restrict__ xloc, u16* __restrict__ knn_out) {
    __shared__ u64 stk[SLOTS][256];
    __shared__ u64 ext[KNN - SLOTS][256];
    const int tid  = threadIdx.x;
    const int q    = tid & (QPB - 1);
    const int seg  = tid >> 5;
    const int blk  = blockIdx.x;
    const int b    = blk >> 7;
    const int i    = ((blk & 127) << 5) | q;
    const float* xb = xloc + (size_t)b * 3 * N_PTS;

    const float xi = xb[i], yi = xb[N_PTS + i], zi = xb[2 * N_PTS + i];
    const float sqi = sq_exact(xi, yi, zi);

    u64 ld[32];
#pragma unroll
    for (int t = 0; t < 32; ++t) ld[t] = ~0ull;
    u64 thr = ~0ull;
    int cnt = 0;

    auto merge_stack = [&]() {
        u64 bd[SLOTS];
#pragma unroll
        for (int t = 0; t < SLOTS; ++t) bd[t] = (t < cnt) ? stk[t][tid] : ~0ull;
#pragma unroll
        for (int k = 2; k <= SLOTS; k <<= 1) {
#pragma unroll
            for (int s = k >> 1; s > 0; s >>= 1) {
#pragma unroll
                for (int t = 0; t < SLOTS; ++t) {
                    int l = t ^ s;
                    if (l > t) {
                        if ((t & k) == 0) cswap64(bd[t], bd[l]);
                        else              cswap64(bd[l], bd[t]);
                    }
                }
            }
        }
#pragma unroll
        for (int t = 0; t < SLOTS; ++t) cswap64(ld[31 - t], bd[t]);
#pragma unroll
        for (int k = 16; k >= 1; k >>= 1) {
#pragma unroll
            for (int t = 0; t < 32; ++t) {
                if ((t & k) == 0) cswap64(ld[t], ld[t | k]);
            }
        }
        thr = ld[KNN - 1];
        cnt = 0;
    };

    const int cbase = seg * SEGN;
    for (int c = 0; c < SEGN; c += 4) {
        const int cc = cbase + c;
        float4 fx = *(const float4*)(xb + cc);
        float4 fy = *(const float4*)(xb + N_PTS + cc);
        float4 fz = *(const float4*)(xb + 2 * N_PTS + cc);
#pragma unroll
        for (int qq = 0; qq < 4; ++qq) {
            float xj = (qq == 0) ? fx.x : (qq == 1) ? fx.y : (qq == 2) ? fx.z : fx.w;
            float yj = (qq == 0) ? fy.x : (qq == 1) ? fy.y : (qq == 2) ? fy.z : fy.w;
            float zj = (qq == 0) ? fz.x : (qq == 1) ? fz.y : (qq == 2) ? fz.z : fz.w;
            float sqj = sq_exact(xj, yj, zj);
            float d = dist_from_sq(xi, yi, zi, sqi, xj, yj, zj, sqj);
            int j = cc + qq;
            u64 key = ((u64)fmap(d) << 12) | (u32)j;
            bool ok = (j != i) && (key < thr);
            if (ok) { stk[cnt][tid] = key; ++cnt; }
        }
        if (__any(cnt >= SLOTS - 3)) merge_stack();
    }
    merge_stack();

#pragma unroll
    for (int t = 0; t < SLOTS; ++t) stk[t][tid] = ld[t];
#pragma unroll
    for (int t = SLOTS; t < KNN; ++t) ext[t - SLOTS][tid] = ld[t];
    __syncthreads();

    if (tid < QPB) {
        const int col0 = tid;
        const int row  = (b << 12) | ((blk & 127) << 5) | tid;
        int  pp[SEG];
        u64  kk[SEG];
#pragma unroll
        for (int s = 0; s < SEG; ++s) { pp[s] = 0; kk[s] = stk[0][col0 + 32 * s]; }
#pragma unroll
        for (int t = 0; t < KNN; ++t) {
            u64 best = kk[0]; int sm = 0;
#pragma unroll
            for (int s = 1; s < SEG; ++s)
                if (kk[s] < best) { best = kk[s]; sm = s; }
            knn_out[(size_t)row * KNN + t] = (u16)(best & 0xFFFu);
#pragma unroll
            for (int s = 0; s < SEG; ++s) {
                if (s == sm) {
                    int p = ++pp[s];
                    int col = col0 + 32 * s;
                    kk[s] = (p < KNN) ? ((p < SLOTS) ? stk[p][col] : ext[p - SLOTS][col])
                                      : ~0ull;
                }
            }
        }
    }
}

__global__ __launch_bounds__(128) void conv_q_kernel(
    const float* __restrict__ xloc,
    const float* __restrict__ xfeat,
    const float* __restrict__ Wrel,
    const float* __restrict__ brel,
    const float* __restrict__ Wroot,
    const u16* __restrict__ knn_in,
    float* __restrict__ out) {
    __shared__ float rowbuf[2][N_PTS];
    const int tid = threadIdx.x;
    const int p   = tid & 31;
    const int qtr = tid >> 5;
    const int blk = blockIdx.x;
    const int b   = blk >> 7;
    const int i   = ((blk & 127) << 5) | p;
    const float* xb = xloc + (size_t)b * 3 * N_PTS;
    const float* fb = xfeat + (size_t)b * 64 * N_PTS;

    if (qtr == 0) {
#pragma unroll
        for (int c = 0; c < 3; ++c)
            out[((size_t)b * 3 + c) * N_PTS + i] = xb[(size_t)c * N_PTS + i];
    }

    u32 kl[KNN / 2];
    const u32* kp = (const u32*)(knn_in + (size_t)((b << 12) | i) * KNN);
#pragma unroll
    for (int w = 0; w < KNN / 2; ++w) kl[w] = kp[w];
    int jj[KNN];
#pragma unroll
    for (int t = 0; t < KNN; ++t) jj[t] = (int)((kl[t >> 1] >> ((t & 1) * 16)) & 0xFFFFu);

    float rel[16], root[16];
#pragma unroll
    for (int c = 0; c < 16; ++c) { rel[c] = 0.f; root[c] = 0.f; }

    auto stage = [&](int f) {
        const float* src = (f < 3) ? (xb + (size_t)f * N_PTS)
                                   : (fb + (size_t)(f - 3) * N_PTS);
        const float4* s4 = (const float4*)src;
        float4* d4 = (float4*)rowbuf[f & 1];
#pragma unroll
        for (int w = 0; w < 8; ++w) {
            int idx = w * 128 + tid;
            d4[idx] = s4[idx];
        }
    };

    stage(0);
    __syncthreads();

    for (int f = 0; f < FIN; ++f) {
        if (f + 1 < FIN) stage(f + 1);
        const float* cur = rowbuf[f & 1];
        float hf = cur[i];
        float af = 0.f;
#pragma unroll
        for (int t = 0; t < KNN; ++t) af += cur[jj[t]];

        const float4* w4r = (const float4*)(Wrel + f * COUT + qtr * 16);
        const float4* w4o = (const float4*)(Wroot + f * COUT + qtr * 16);
#pragma unroll
        for (int c4 = 0; c4 < 4; ++c4) {
            float4 wr = w4r[c4], wo = w4o[c4];
            rel[c4 * 4 + 0] += af * wr.x;  root[c4 * 4 + 0] += hf * wo.x;
            rel[c4 * 4 + 1] += af * wr.y;  root[c4 * 4 + 1] += hf * wo.y;
            rel[c4 * 4 + 2] += af * wr.z;  root[c4 * 4 + 2] += hf * wo.z;
            rel[c4 * 4 + 3] += af * wr.w;  root[c4 * 4 + 3] += hf * wo.w;
        }
        __syncthreads();
    }

    const size_t ob = (size_t)NB * 3 * N_PTS + (size_t)b * COUT * N_PTS;
#pragma unroll
    for (int c = 0; c < 16; ++c) {
        int cc = qtr * 16 + c;
        float acc = (rel[c] + brel[cc]) + root[c];
        out[ob + (size_t)cc * N_PTS + i] = fmaxf(acc, 0.f);
    }
}

// ---------------- Last-resort fallback: proven round-7 monolith ----------------
__device__ __forceinline__ void insert3(float d, int c,
                                        float& v0, float& v1, float& v2,
                                        int& c0, int& c1, int& c2) {
    if (d < v2) {
        if (d < v1) {
            if (d < v0) { v2 = v1; c2 = c1; v1 = v0; c1 = c0; v0 = d; c0 = c; }
            else        { v2 = v1; c2 = c1; v1 = d;  c1 = c; }
        } else          { v2 = d;  c2 = c; }
    }
}

__global__ __launch_bounds__(64) void pcd_all(
    const float* __restrict__ xloc,
    const float* __restrict__ xfeat,
    const float* __restrict__ Wrel,
    const float* __restrict__ brel,
    const float* __restrict__ Wroot,
    float* __restrict__ out) {
    const int lane = threadIdx.x;
    const int row  = blockIdx.x;
    const int b    = row >> 12;
    const int i    = row & (N_PTS - 1);
    const float* xb = xloc + (size_t)b * 3 * N_PTS;

    if (lane < 3) {
        out[((size_t)b * 3 + lane) * N_PTS + i] = xb[(size_t)lane * N_PTS + i];
    }

    const float xi  = xb[i];
    const float yi  = xb[N_PTS + i];
    const float zi  = xb[2 * N_PTS + i];
    const float sqi = sq_exact(xi, yi, zi);

    float v0 = 1e30f, v1 = 1e30f, v2 = 1e30f;
    int   c0 = -1,    c1 = -1,    c2 = -1;

    for (int s = 0; s < 16; ++s) {
        int jb = s * 256 + lane * 4;
        float4 fx = *(const float4*)(xb + jb);
        float4 fy = *(const float4*)(xb + N_PTS + jb);
        float4 fz = *(const float4*)(xb + 2 * N_PTS + jb);
#pragma unroll
        for (int q = 0; q < 4; ++q) {
            float xj = (q == 0) ? fx.x : (q == 1) ? fx.y : (q == 2) ? fx.z : fx.w;
            float yj = (q == 0) ? fy.x : (q == 1) ? fy.y : (q == 2) ? fy.z : fy.w;
            float zj = (q == 0) ? fz.x : (q == 1) ? fz.y : (q == 2) ? fz.z : fz.w;
            int j = jb + q;
            float d = (j == i) ? 1e30f : dist_exact(xi, yi, zi, sqi, xj, yj, zj);
            insert3(d, s * 4 + q, v0, v1, v2, c0, c1, c2);
        }
    }

    u64 taken = 0;
    __shared__ int knn[KNN];

    for (int t = 0; t < KNN; ++t) {
        float bv = v0;
        int   bj = (c0 >= 0) ? (((c0 >> 2) << 8) + lane * 4 + (c0 & 3)) : (N_PTS - 1);
#pragma unroll
        for (int m = 1; m < 64; m <<= 1) {
            float ov = __shfl_xor(bv, m);
            int   oj = __shfl_xor(bj, m);
            if (ov < bv || (ov == bv && oj < bj)) { bv = ov; bj = oj; }
        }
        if (lane == 0) knn[t] = bj & (N_PTS - 1);
        int owner = (bj >> 2) & 63;
        if (lane == owner) {
            int cw = (((bj >> 8) << 2) | (bj & 3)) & 63;
            taken |= (1ull << cw);
            v0 = v1; c0 = c1; v1 = v2; c1 = c2; v2 = 1e30f; c2 = -1;
            if (v0 >= 1e30f) {
                v0 = v1 = v2 = 1e30f; c0 = c1 = c2 = -1;
                for (int s = 0; s < 16; ++s) {
                    int jb = s * 256 + lane * 4;
                    float4 fx = *(const float4*)(xb + jb);
                    float4 fy = *(const float4*)(xb + N_PTS + jb);
                    float4 fz = *(const float4*)(xb + 2 * N_PTS + jb);
#pragma unroll
                    for (int q = 0; q < 4; ++q) {
                        int cc = s * 4 + q;
                        if ((taken >> cc) & 1ull) continue;
                        int j = jb + q;
                        if (j == i) continue;
                        float xj = (q == 0) ? fx.x : (q == 1) ? fx.y : (q == 2) ? fx.z : fx.w;
                        float yj = (q == 0) ? fy.x : (q == 1) ? fy.y : (q == 2) ? fy.z : fy.w;
                        float zj = (q == 0) ? fz.x : (q == 1) ? fz.y : (q == 2) ? fz.z : fz.w;
                        float d = dist_exact(xi, yi, zi, sqi, xj, yj, zj);
                        insert3(d, cc, v0, v1, v2, c0, c1, c2);
                    }
                }
            }
        }
    }

    __syncthreads();

    __shared__ float aggf[FIN + 1];
    __shared__ float hif[FIN + 1];

    const float* xfb = xfeat + ((size_t)b * 64 + lane) * N_PTS;
    const float* xlb = xb + (size_t)(lane < 3 ? lane : 0) * N_PTS;
    float af = 0.f, al = 0.f;
    for (int t = 0; t < KNN; ++t) {
        int j = knn[t];
        af += xfb[j];
        if (lane < 3) al += xlb[j];
    }
    aggf[3 + lane] = af;
    hif[3 + lane]  = xfb[i];
    if (lane < 3) { aggf[lane] = al; hif[lane] = xlb[i]; }
    __syncthreads();

    float acc_rel = 0.f, acc_root = 0.f;
    for (int f = 0; f < FIN; ++f) {
        acc_rel  += aggf[f] * Wrel[f * COUT + lane];
        acc_root += hif[f]  * Wroot[f * COUT + lane];
    }
    float acc = (acc_rel + brel[lane]) + acc_root;
    acc = fmaxf(acc, 0.0f);
    out[(size_t)NB * 3 * N_PTS + ((((size_t)b << 6) | lane) << 12) + i] = acc;
}

extern "C" void kernel_launch(void* const* d_in, const int* in_sizes, int n_in,
                              void* d_out, int out_size, void* d_ws, size_t ws_size,
                              hipStream_t stream) {
    const float* xloc  = nullptr;
    const float* xfeat = nullptr;
    const float* Wrel  = nullptr;
    const float* brel  = nullptr;
    const float* Wroot = nullptr;
    for (int idx = 0; idx < n_in; ++idx) {
        const long long s = in_sizes[idx];
        const float* p = (const float*)d_in[idx];
        if (s == 98304LL || s == 393216LL)          { xloc = p; }
        else if (s == 2097152LL || s == 8388608LL)  { xfeat = p; }
        else if (s == 4288LL || s == 17152LL)       { if (!Wrel) Wrel = p; else Wroot = p; }
        else if (s == 64LL || s == 256LL)           { brel = p; }
    }
    if (!xloc || !xfeat || !Wrel || !brel || !Wroot) {
        xloc  = (const float*)d_in[0];
        xfeat = (const float*)d_in[1];
        Wrel  = (const float*)d_in[2];
        brel  = (const float*)d_in[3];
        Wroot = (const float*)d_in[4];
    }

    if (d_ws != nullptr && ws_size >= (size_t)WS_NEED) {
        u16*    knn_ws = (u16*)d_ws;
        float*  ft     = (float*)((char*)d_ws + FT_OFF);
        float4* pack   = (float4*)((char*)d_ws + PK_OFF);
        transpose_kernel<<<dim3(NB * 64), dim3(256), 0, stream>>>(
            xloc, xfeat, ft, pack, (float*)d_out);
        knn_pack_kernel<<<dim3(NB * 128), dim3(256), 0, stream>>>(pack, knn_ws);
        conv_g_kernel<<<dim3(NB * 128), dim3(128), 0, stream>>>(
            Wrel, brel, Wroot, knn_ws, ft, pack, (float*)d_out);
    } else if (d_ws != nullptr && ws_size >= (size_t)KNN_BYTES) {
        u16* knn_ws = (u16*)d_ws;
        knn_seg8_kernel<<<dim3(NB * 128), dim3(256), 0, stream>>>(xloc, knn_ws);
        conv_q_kernel<<<dim3(NB * 128), dim3(128), 0, stream>>>(
            xloc, xfeat, Wrel, brel, Wroot, knn_ws, (float*)d_out);
    } else {
        pcd_all<<<dim3(NB * N_PTS), dim3(64), 0, stream>>>(
            xloc, xfeat, Wrel, brel, Wroot, (float*)d_out);
    }
}

// Round 16
// 285.548 us; speedup vs baseline: 1.7102x; 1.2409x over previous
//
#include <hip/hip_runtime.h>

#define N_PTS 4096
#define NB    8
#define KNN   20
#define FIN   67
#define COUT  64
#define SEG   4
#define SEGN  (N_PTS / SEG)   // 1024 candidates per segment-thread
#define SLOTS 16              // LDS stack slots per thread

typedef unsigned short u16;
typedef unsigned int   u32;
typedef unsigned long long u64;

// ws layout (bytes)
#define KNN_BYTES 1310720u                      // 8*4096*20*2
#define FT_OFF    1310720u                      // ft[b][n][64] f32 = 8388608
#define PK_OFF    (FT_OFF + 8388608u)           // pack[b][n] float4 = 524288
#define WS_NEED   (PK_OFF + 524288u)            // 10223616

__device__ __forceinline__ float finf() { return __uint_as_float(0x7f800000u); }

// Order-preserving f32 -> u32 map (total order, matches IEEE < on non-NaN).
__device__ __forceinline__ u32 fmap(float f) {
    u32 b = __float_as_uint(f);
    return b ^ ((u32)((int)b >> 31) | 0x80000000u);
}

// sq = (x*x + y*y) + z*z, all f32, no FMA (matches np op order).
__device__ __forceinline__ float sq_exact(float x, float y, float z) {
#pragma clang fp contract(off)
    float s = (x * x + y * y) + z * z;
    return s;
}

// dist = (sq_i - 2*dot) + sq_j, dot = (x_i*x_j + y_i*y_j) + z_i*z_j, no FMA.
__device__ __forceinline__ float dist_from_sq(float xi, float yi, float zi, float sqi,
                                              float xj, float yj, float zj, float sqj) {
#pragma clang fp contract(off)
    float d0 = xi * xj, d1 = yi * yj, d2 = zi * zj;
    float dot = (d0 + d1) + d2;
    float d = (sqi - 2.0f * dot) + sqj;
    return d;
}

__device__ __forceinline__ float dist_exact(float xi, float yi, float zi, float sqi,
                                            float xj, float yj, float zj) {
#pragma clang fp contract(off)
    float d0 = xi * xj, d1 = yi * yj, d2 = zi * zj;
    float dot = (d0 + d1) + d2;
    float sqj = (xj * xj + yj * yj) + zj * zj;
    float d = (sqi - 2.0f * dot) + sqj;
    return d;
}

// u64 key = fmap(d) << 12 | j  — plain u64 < is EXACT (d, j) lex order.
__device__ __forceinline__ void cswap64(u64& a, u64& b) {
    bool sw = b < a;
    u64 na = sw ? b : a, nb = sw ? a : b;
    a = na; b = nb;
}

// ---------------- Kernel 0: transpose/pack + out0 passthrough ----------------
__global__ __launch_bounds__(256) void transpose_kernel(
    const float* __restrict__ xloc, const float* __restrict__ xfeat,
    float* __restrict__ ft, float4* __restrict__ pack, float* __restrict__ out) {
    __shared__ float tile[64][65];
    const int tid = threadIdx.x;
    const int blk = blockIdx.x;               // b*64 + ntile
    const int b   = blk >> 6;
    const int n0  = (blk & 63) << 6;
    const int tx  = tid & 63, w = tid >> 6;

    if (tid < 48) {
        int idx4 = blk * 48 + tid;            // 512*48 float4 = 98304 f32
        ((float4*)out)[idx4] = ((const float4*)xloc)[idx4];
    }
    if (w == 0) {
        float x = xloc[((size_t)b * 3 + 0) * N_PTS + n0 + tx];
        float y = xloc[((size_t)b * 3 + 1) * N_PTS + n0 + tx];
        float z = xloc[((size_t)b * 3 + 2) * N_PTS + n0 + tx];
        pack[((size_t)b << 12) + n0 + tx] = make_float4(x, y, z, sq_exact(x, y, z));
    }
#pragma unroll
    for (int k = 0; k < 16; ++k) {
        int c = w * 16 + k;
        tile[tx][c] = xfeat[((size_t)(b << 6) + c) * N_PTS + n0 + tx];
    }
    __syncthreads();
#pragma unroll
    for (int k = 0; k < 16; ++k) {
        int n = w * 16 + k;
        ft[(((size_t)(b << 12)) + n0 + n) * 64 + tx] = tile[n][tx];
    }
}

// ---------------- Kernel 1: kNN — wave-uniform segments, scalar cand loads ----
// Block = 256 threads = 4 waves; wave w = segment w (1024 candidates), lane =
// query (64 per block). Candidate addresses are wave-uniform (readfirstlane)
// -> SMEM s_load path, zero per-lane addr math. Gate is a single float cmp
// vs the 21st-best distance (exact by ascending-j ties); the u64 key is built
// only under the insert mask. Self (d == +0.0) flows through the scan and is
// compacted out of the exact top-21 at publish.
__global__ __launch_bounds__(256) void knn_v2_kernel(
    const float4* __restrict__ pack, u16* __restrict__ knn_out) {
    __shared__ u64 stk[SLOTS][256];           // 32 KB, bank-free SoA
    __shared__ u64 ext[KNN - SLOTS][256];     // 8 KB  (publish slots 16..19)
    const int tid  = threadIdx.x;
    const int lane = tid & 63;                // query within tile
    const int blk  = blockIdx.x;              // b*64 + qtile
    const int b    = blk >> 6;
    const int tile = blk & 63;
    const int i    = (tile << 6) | lane;
    const float4* pb = pack + ((size_t)b << 12);

    // Wave-uniform segment base -> scalar loads in the hot loop.
    const int segu  = __builtin_amdgcn_readfirstlane(tid >> 6);
    const float4* base = pb + segu * SEGN;

    const float4 qp = pb[i];
    const float xi = qp.x, yi = qp.y, zi = qp.z, sqi = qp.w;

    u64 ld[32];
#pragma unroll
    for (int t = 0; t < 32; ++t) ld[t] = ~0ull;
    float thr = finf();
    int cnt = 0;

    auto merge_stack = [&]() {
        u64 bd[SLOTS];
#pragma unroll
        for (int t = 0; t < SLOTS; ++t) bd[t] = (t < cnt) ? stk[t][tid] : ~0ull;
#pragma unroll
        for (int k = 2; k <= SLOTS; k <<= 1) {
#pragma unroll
            for (int s = k >> 1; s > 0; s >>= 1) {
#pragma unroll
                for (int t = 0; t < SLOTS; ++t) {
                    int l = t ^ s;
                    if (l > t) {
                        if ((t & k) == 0) cswap64(bd[t], bd[l]);
                        else              cswap64(bd[l], bd[t]);
                    }
                }
            }
        }
#pragma unroll
        for (int t = 0; t < SLOTS; ++t) cswap64(ld[31 - t], bd[t]);
#pragma unroll
        for (int k = 16; k >= 1; k >>= 1) {
#pragma unroll
            for (int t = 0; t < 32; ++t) {
                if ((t & k) == 0) cswap64(ld[t], ld[t | k]);
            }
        }
        // thr = distance of the 21st-best (ld[KNN]); guard padding (all-ones).
        u32 m = (u32)(ld[KNN] >> 12);
        u32 db = m ^ ((m & 0x80000000u) ? 0x80000000u : 0xFFFFFFFFu);
        thr = (m == 0xFFFFFFFFu) ? finf() : __uint_as_float(db);
        cnt = 0;
    };

    const int jbase = segu * SEGN;
    for (int c = 0; c < SEGN; c += 4) {
        float4 p0 = base[c + 0], p1 = base[c + 1];
        float4 p2 = base[c + 2], p3 = base[c + 3];
#pragma unroll
        for (int qq = 0; qq < 4; ++qq) {
            float4 pk = (qq == 0) ? p0 : (qq == 1) ? p1 : (qq == 2) ? p2 : p3;
            float d = dist_from_sq(xi, yi, zi, sqi, pk.x, pk.y, pk.z, pk.w);
            // Float-only gate vs 21st-best: a rejected d == thr candidate has
            // larger j (ascending scan) => key rank > 21 forever. Self is NOT
            // excluded here (d_self == +0.0 inserts; filtered at publish).
            if (d < thr) {
                u64 key = ((u64)fmap(d) << 12) | (u32)(jbase + c + qq);
                stk[cnt][tid] = key;
                ++cnt;
            }
        }
        // Entering a chunk all lanes have cnt <= 12; +4 max => <= 16. ✓
        if (__any(cnt >= SLOTS - 3)) merge_stack();
    }
    merge_stack();                            // drain

    // Publish exact top-20 EXCLUDING self: compact ld[0..20] (exact top-21).
    u64 pub[KNN];
    {
        bool sf = false;
#pragma unroll
        for (int t = 0; t < KNN + 1; ++t) {
            bool isself = ((u32)(ld[t] & 0xFFFull) == (u32)i);
            sf = sf || isself;
            if (t < KNN) pub[t] = sf ? ld[t + 1] : ld[t];
        }
    }
#pragma unroll
    for (int t = 0; t < SLOTS; ++t) stk[t][tid] = pub[t];
#pragma unroll
    for (int t = SLOTS; t < KNN; ++t) ext[t - SLOTS][tid] = pub[t];
    __syncthreads();

    // Exact 4-way tournament merge per query (threads 0..63, wave 0).
    if (tid < 64) {
        const int q = tid;
        const int row = (b << 12) | (tile << 6) | q;
        int pp[SEG];
        u64 kk[SEG];
#pragma unroll
        for (int s = 0; s < SEG; ++s) { pp[s] = 0; kk[s] = stk[0][q + 64 * s]; }
#pragma unroll
        for (int t = 0; t < KNN; ++t) {
            u64 best = kk[0]; int sm = 0;
#pragma unroll
            for (int s = 1; s < SEG; ++s)
                if (kk[s] < best) { best = kk[s]; sm = s; }
            knn_out[(size_t)row * KNN + t] = (u16)(best & 0xFFFull);
#pragma unroll
            for (int s = 0; s < SEG; ++s) {
                if (s == sm) {
                    int p = ++pp[s];
                    int col = q + 64 * s;
                    kk[s] = (p < KNN) ? ((p < SLOTS) ? stk[p][col] : ext[p - SLOTS][col])
                                      : ~0ull;
                }
            }
        }
    }
}

// ---------------- Kernel 2: conv — 16-pt tiles, LDS index preload ----------------
// 2048 blocks x 128 threads -> 8 blocks/CU, 16 waves/CU (r15 conv had 4 blocks).
// Phase 1: wave w gathers 8 points; lane = channel; neighbor indices read from
// LDS (preloaded coalesced) instead of 320 uniform-address VMEM loads.
// Phase 2: thread = (channel-eighth, point); coalesced out writes.
__global__ __launch_bounds__(128) void conv_g2_kernel(
    const float* __restrict__ Wrel,
    const float* __restrict__ brel,
    const float* __restrict__ Wroot,
    const u16* __restrict__ knn_in,
    const float* __restrict__ ft,
    const float4* __restrict__ pack,
    float* __restrict__ out) {
    __shared__ float aggf[16][69];
    __shared__ float hif[16][69];
    __shared__ u16 idx[16 * KNN];             // 640 B
    const int tid = threadIdx.x;
    const int blk = blockIdx.x;               // b*256 + tile
    const int b   = blk >> 8;
    const int i0  = (blk & 255) << 4;
    const int lane = tid & 63, w = tid >> 6;
    const float* ftb = ft + (((size_t)b << 12)) * 64;
    const float* pkb = (const float*)(pack + ((size_t)b << 12));

    // Preload the tile's 16x20 neighbor indices (coalesced u32 loads).
    {
        const u32* src = (const u32*)(knn_in + (size_t)((b << 12) | i0) * KNN);
        for (int k = tid; k < 16 * KNN / 2; k += 128) ((u32*)idx)[k] = src[k];
    }
    __syncthreads();

#pragma unroll
    for (int pp = 0; pp < 8; ++pp) {
        int p = w * 8 + pp;
        int i = i0 + p;
        float af = 0.f, al = 0.f;
        float hfv = ftb[(size_t)i * 64 + lane];
        float hlv = (lane < 3) ? pkb[(size_t)i * 4 + lane] : 0.f;
#pragma unroll
        for (int t = 0; t < KNN; ++t) {       // ascending (dist, idx) order
            int j = idx[p * KNN + t];
            af += ftb[(size_t)j * 64 + lane];
            if (lane < 3) al += pkb[(size_t)j * 4 + lane];
        }
        aggf[p][3 + lane] = af;
        hif[p][3 + lane]  = hfv;
        if (lane < 3) { aggf[p][lane] = al; hif[p][lane] = hlv; }
    }
    __syncthreads();

    const int p2 = tid & 15, oct = tid >> 4;  // 8 channels per thread
    const int i2 = i0 + p2;
    float rel[8], root[8];
#pragma unroll
    for (int c = 0; c < 8; ++c) { rel[c] = 0.f; root[c] = 0.f; }
    for (int f = 0; f < FIN; ++f) {
        float a = aggf[p2][f];
        float h = hif[p2][f];
        const float4* w4r = (const float4*)(Wrel + f * COUT + oct * 8);
        const float4* w4o = (const float4*)(Wroot + f * COUT + oct * 8);
#pragma unroll
        for (int c4 = 0; c4 < 2; ++c4) {
            float4 wr = w4r[c4], wo = w4o[c4];
            rel[c4 * 4 + 0] += a * wr.x;  root[c4 * 4 + 0] += h * wo.x;
            rel[c4 * 4 + 1] += a * wr.y;  root[c4 * 4 + 1] += h * wo.y;
            rel[c4 * 4 + 2] += a * wr.z;  root[c4 * 4 + 2] += h * wo.z;
            rel[c4 * 4 + 3] += a * wr.w;  root[c4 * 4 + 3] += h * wo.w;
        }
    }
    const size_t ob = (size_t)NB * 3 * N_PTS + (size_t)b * COUT * N_PTS;
#pragma unroll
    for (int c = 0; c < 8; ++c) {
        int cc = oct * 8 + c;
        float acc = (rel[c] + brel[cc]) + root[c];  // einsum + b_rel + einsum order
        out[ob + (size_t)cc * N_PTS + i2] = fmaxf(acc, 0.f);
    }
}

// ================= r14 fallback path (proven, 379us) =================
__global__ __launch_bounds__(256) void knn_seg8_kernel(
    const float* __restrict__ xloc, u16* __restrict__ knn_out) {
    __shared__ u64 stk[SLOTS][256];
    __shared__ u64 ext[KNN - SLOTS][256];
    const int tid  = threadIdx.x;
    const int q    = tid & 31;
    const int seg  = tid >> 5;
    const int blk  = blockIdx.x;
    const int b    = blk >> 7;
    const int i    = ((blk & 127) << 5) | q;
    const float* xb = xloc + (size_t)b * 3 * N_PTS;

    const float xi = xb[i], yi = xb[N_PTS + i], zi = xb[2 * N_PTS + i];
    const float sqi = sq_exact(xi, yi, zi);

    u64 ld[32];
#pragma unroll
    for (int t = 0; t < 32; ++t) ld[t] = ~0ull;
    u64 thr = ~0ull;
    int cnt = 0;

    auto merge_stack = [&]() {
        u64 bd[SLOTS];
#pragma unroll
        for (int t = 0; t < SLOTS; ++t) bd[t] = (t < cnt) ? stk[t][tid] : ~0ull;
#pragma unroll
        for (int k = 2; k <= SLOTS; k <<= 1) {
#pragma unroll
            for (int s = k >> 1; s > 0; s >>= 1) {
#pragma unroll
                for (int t = 0; t < SLOTS; ++t) {
                    int l = t ^ s;
                    if (l > t) {
                        if ((t & k) == 0) cswap64(bd[t], bd[l]);
                        else              cswap64(bd[l], bd[t]);
                    }
                }
            }
        }
#pragma unroll
        for (int t = 0; t < SLOTS; ++t) cswap64(ld[31 - t], bd[t]);
#pragma unroll
        for (int k = 16; k >= 1; k >>= 1) {
#pragma unroll
            for (int t = 0; t < 32; ++t) {
                if ((t & k) == 0) cswap64(ld[t], ld[t | k]);
            }
        }
        thr = ld[KNN - 1];
        cnt = 0;
    };

    const int cbase = seg * 512;
    for (int c = 0; c < 512; c += 4) {
        const int cc = cbase + c;
        float4 fx = *(const float4*)(xb + cc);
        float4 fy = *(const float4*)(xb + N_PTS + cc);
        float4 fz = *(const float4*)(xb + 2 * N_PTS + cc);
#pragma unroll
        for (int qq = 0; qq < 4; ++qq) {
            float xj = (qq == 0) ? fx.x : (qq == 1) ? fx.y : (qq == 2) ? fx.z : fx.w;
            float yj = (qq == 0) ? fy.x : (qq == 1) ? fy.y : (qq == 2) ? fy.z : fy.w;
            float zj = (qq == 0) ? fz.x : (qq == 1) ? fz.y : (qq == 2) ? fz.z : fz.w;
            float sqj = sq_exact(xj, yj, zj);
            float d = dist_from_sq(xi, yi, zi, sqi, xj, yj, zj, sqj);
            int j = cc + qq;
            u64 key = ((u64)fmap(d) << 12) | (u32)j;
            bool ok = (j != i) && (key < thr);
            if (ok) { stk[cnt][tid] = key; ++cnt; }
        }
        if (__any(cnt >= SLOTS - 3)) merge_stack();
    }
    merge_stack();

#pragma unroll
    for (int t = 0; t < SLOTS; ++t) stk[t][tid] = ld[t];
#pragma unroll
    for (int t = SLOTS; t < KNN; ++t) ext[t - SLOTS][tid] = ld[t];
    __syncthreads();

    if (tid < 32) {
        const int col0 = tid;
        const int row  = (b << 12) | ((blk & 127) << 5) | tid;
        int  pp[8];
        u64  kk[8];
#pragma unroll
        for (int s = 0; s < 8; ++s) { pp[s] = 0; kk[s] = stk[0][col0 + 32 * s]; }
#pragma unroll
        for (int t = 0; t < KNN; ++t) {
            u64 best = kk[0]; int sm = 0;
#pragma unroll
            for (int s = 1; s < 8; ++s)
                if (kk[s] < best) { best = kk[s]; sm = s; }
            knn_out[(size_t)row * KNN + t] = (u16)(best & 0xFFFu);
#pragma unroll
            for (int s = 0; s < 8; ++s) {
                if (s == sm) {
                    int p = ++pp[s];
                    int col = col0 + 32 * s;
                    kk[s] = (p < KNN) ? ((p < SLOTS) ? stk[p][col] : ext[p - SLOTS][col])
                                      : ~0ull;
                }
            }
        }
    }
}

__global__ __launch_bounds__(128) void conv_q_kernel(
    const float* __restrict__ xloc,
    const float* __restrict__ xfeat,
    const float* __restrict__ Wrel,
    const float* __restrict__ brel,
    const float* __restrict__ Wroot,
    const u16* __restrict__ knn_in,
    float* __restrict__ out) {
    __shared__ float rowbuf[2][N_PTS];
    const int tid = threadIdx.x;
    const int p   = tid & 31;
    const int qtr = tid >> 5;
    const int blk = blockIdx.x;
    const int b   = blk >> 7;
    const int i   = ((blk & 127) << 5) | p;
    const float* xb = xloc + (size_t)b * 3 * N_PTS;
    const float* fb = xfeat + (size_t)b * 64 * N_PTS;

    if (qtr == 0) {
#pragma unroll
        for (int c = 0; c < 3; ++c)
            out[((size_t)b * 3 + c) * N_PTS + i] = xb[(size_t)c * N_PTS + i];
    }

    u32 kl[KNN / 2];
    const u32* kp = (const u32*)(knn_in + (size_t)((b << 12) | i) * KNN);
#pragma unroll
    for (int w = 0; w < KNN / 2; ++w) kl[w] = kp[w];
    int jj[KNN];
#pragma unroll
    for (int t = 0; t < KNN; ++t) jj[t] = (int)((kl[t >> 1] >> ((t & 1) * 16)) & 0xFFFFu);

    float rel[16], root[16];
#pragma unroll
    for (int c = 0; c < 16; ++c) { rel[c] = 0.f; root[c] = 0.f; }

    auto stage = [&](int f) {
        const float* src = (f < 3) ? (xb + (size_t)f * N_PTS)
                                   : (fb + (size_t)(f - 3) * N_PTS);
        const float4* s4 = (const float4*)src;
        float4* d4 = (float4*)rowbuf[f & 1];
#pragma unroll
        for (int w = 0; w < 8; ++w) {
            int idxw = w * 128 + tid;
            d4[idxw] = s4[idxw];
        }
    };

    stage(0);
    __syncthreads();

    for (int f = 0; f < FIN; ++f) {
        if (f + 1 < FIN) stage(f + 1);
        const float* cur = rowbuf[f & 1];
        float hf = cur[i];
        float af = 0.f;
#pragma unroll
        for (int t = 0; t < KNN; ++t) af += cur[jj[t]];

        const float4* w4r = (const float4*)(Wrel + f * COUT + qtr * 16);
        const float4* w4o = (const float4*)(Wroot + f * COUT + qtr * 16);
#pragma unroll
        for (int c4 = 0; c4 < 4; ++c4) {
            float4 wr = w4r[c4], wo = w4o[c4];
            rel[c4 * 4 + 0] += af * wr.x;  root[c4 * 4 + 0] += hf * wo.x;
            rel[c4 * 4 + 1] += af * wr.y;  root[c4 * 4 + 1] += hf * wo.y;
            rel[c4 * 4 + 2] += af * wr.z;  root[c4 * 4 + 2] += hf * wo.z;
            rel[c4 * 4 + 3] += af * wr.w;  root[c4 * 4 + 3] += hf * wo.w;
        }
        __syncthreads();
    }

    const size_t ob = (size_t)NB * 3 * N_PTS + (size_t)b * COUT * N_PTS;
#pragma unroll
    for (int c = 0; c < 16; ++c) {
        int cc = qtr * 16 + c;
        float acc = (rel[c] + brel[cc]) + root[c];
        out[ob + (size_t)cc * N_PTS + i] = fmaxf(acc, 0.f);
    }
}

// ---------------- Last-resort fallback: proven round-7 monolith ----------------
__device__ __forceinline__ void insert3(float d, int c,
                                        float& v0, float& v1, float& v2,
                                        int& c0, int& c1, int& c2) {
    if (d < v2) {
        if (d < v1) {
            if (d < v0) { v2 = v1; c2 = c1; v1 = v0; c1 = c0; v0 = d; c0 = c; }
            else        { v2 = v1; c2 = c1; v1 = d;  c1 = c; }
        } else          { v2 = d;  c2 = c; }
    }
}

__global__ __launch_bounds__(64) void pcd_all(
    const float* __restrict__ xloc,
    const float* __restrict__ xfeat,
    const float* __restrict__ Wrel,
    const float* __restrict__ brel,
    const float* __restrict__ Wroot,
    float* __restrict__ out) {
    const int lane = threadIdx.x;
    const int row  = blockIdx.x;
    const int b    = row >> 12;
    const int i    = row & (N_PTS - 1);
    const float* xb = xloc + (size_t)b * 3 * N_PTS;

    if (lane < 3) {
        out[((size_t)b * 3 + lane) * N_PTS + i] = xb[(size_t)lane * N_PTS + i];
    }

    const float xi  = xb[i];
    const float yi  = xb[N_PTS + i];
    const float zi  = xb[2 * N_PTS + i];
    const float sqi = sq_exact(xi, yi, zi);

    float v0 = 1e30f, v1 = 1e30f, v2 = 1e30f;
    int   c0 = -1,    c1 = -1,    c2 = -1;

    for (int s = 0; s < 16; ++s) {
        int jb = s * 256 + lane * 4;
        float4 fx = *(const float4*)(xb + jb);
        float4 fy = *(const float4*)(xb + N_PTS + jb);
        float4 fz = *(const float4*)(xb + 2 * N_PTS + jb);
#pragma unroll
        for (int q = 0; q < 4; ++q) {
            float xj = (q == 0) ? fx.x : (q == 1) ? fx.y : (q == 2) ? fx.z : fx.w;
            float yj = (q == 0) ? fy.x : (q == 1) ? fy.y : (q == 2) ? fy.z : fy.w;
            float zj = (q == 0) ? fz.x : (q == 1) ? fz.y : (q == 2) ? fz.z : fz.w;
            int j = jb + q;
            float d = (j == i) ? 1e30f : dist_exact(xi, yi, zi, sqi, xj, yj, zj);
            insert3(d, s * 4 + q, v0, v1, v2, c0, c1, c2);
        }
    }

    u64 taken = 0;
    __shared__ int knn[KNN];

    for (int t = 0; t < KNN; ++t) {
        float bv = v0;
        int   bj = (c0 >= 0) ? (((c0 >> 2) << 8) + lane * 4 + (c0 & 3)) : (N_PTS - 1);
#pragma unroll
        for (int m = 1; m < 64; m <<= 1) {
            float ov = __shfl_xor(bv, m);
            int   oj = __shfl_xor(bj, m);
            if (ov < bv || (ov == bv && oj < bj)) { bv = ov; bj = oj; }
        }
        if (lane == 0) knn[t] = bj & (N_PTS - 1);
        int owner = (bj >> 2) & 63;
        if (lane == owner) {
            int cw = (((bj >> 8) << 2) | (bj & 3)) & 63;
            taken |= (1ull << cw);
            v0 = v1; c0 = c1; v1 = v2; c1 = c2; v2 = 1e30f; c2 = -1;
            if (v0 >= 1e30f) {
                v0 = v1 = v2 = 1e30f; c0 = c1 = c2 = -1;
                for (int s = 0; s < 16; ++s) {
                    int jb = s * 256 + lane * 4;
                    float4 fx = *(const float4*)(xb + jb);
                    float4 fy = *(const float4*)(xb + N_PTS + jb);
                    float4 fz = *(const float4*)(xb + 2 * N_PTS + jb);
#pragma unroll
                    for (int q = 0; q < 4; ++q) {
                        int cc = s * 4 + q;
                        if ((taken >> cc) & 1ull) continue;
                        int j = jb + q;
                        if (j == i) continue;
                        float xj = (q == 0) ? fx.x : (q == 1) ? fx.y : (q == 2) ? fx.z : fx.w;
                        float yj = (q == 0) ? fy.x : (q == 1) ? fy.y : (q == 2) ? fy.z : fy.w;
                        float zj = (q == 0) ? fz.x : (q == 1) ? fz.y : (q == 2) ? fz.z : fz.w;
                        float d = dist_exact(xi, yi, zi, sqi, xj, yj, zj);
                        insert3(d, cc, v0, v1, v2, c0, c1, c2);
                    }
                }
            }
        }
    }

    __syncthreads();

    __shared__ float aggf[FIN + 1];
    __shared__ float hif[FIN + 1];

    const float* xfb = xfeat + ((size_t)b * 64 + lane) * N_PTS;
    const float* xlb = xb + (size_t)(lane < 3 ? lane : 0) * N_PTS;
    float af = 0.f, al = 0.f;
    for (int t = 0; t < KNN; ++t) {
        int j = knn[t];
        af += xfb[j];
        if (lane < 3) al += xlb[j];
    }
    aggf[3 + lane] = af;
    hif[3 + lane]  = xfb[i];
    if (lane < 3) { aggf[lane] = al; hif[lane] = xlb[i]; }
    __syncthreads();

    float acc_rel = 0.f, acc_root = 0.f;
    for (int f = 0; f < FIN; ++f) {
        acc_rel  += aggf[f] * Wrel[f * COUT + lane];
        acc_root += hif[f]  * Wroot[f * COUT + lane];
    }
    float acc = (acc_rel + brel[lane]) + acc_root;
    acc = fmaxf(acc, 0.0f);
    out[(size_t)NB * 3 * N_PTS + ((((size_t)b << 6) | lane) << 12) + i] = acc;
}

extern "C" void kernel_launch(void* const* d_in, const int* in_sizes, int n_in,
                              void* d_out, int out_size, void* d_ws, size_t ws_size,
                              hipStream_t stream) {
    const float* xloc  = nullptr;
    const float* xfeat = nullptr;
    const float* Wrel  = nullptr;
    const float* brel  = nullptr;
    const float* Wroot = nullptr;
    for (int idx = 0; idx < n_in; ++idx) {
        const long long s = in_sizes[idx];
        const float* p = (const float*)d_in[idx];
        if (s == 98304LL || s == 393216LL)          { xloc = p; }
        else if (s == 2097152LL || s == 8388608LL)  { xfeat = p; }
        else if (s == 4288LL || s == 17152LL)       { if (!Wrel) Wrel = p; else Wroot = p; }
        else if (s == 64LL || s == 256LL)           { brel = p; }
    }
    if (!xloc || !xfeat || !Wrel || !brel || !Wroot) {
        xloc  = (const float*)d_in[0];
        xfeat = (const float*)d_in[1];
        Wrel  = (const float*)d_in[2];
        brel  = (const float*)d_in[3];
        Wroot = (const float*)d_in[4];
    }

    if (d_ws != nullptr && ws_size >= (size_t)WS_NEED) {
        u16*    knn_ws = (u16*)d_ws;
        float*  ft     = (float*)((char*)d_ws + FT_OFF);
        float4* pack   = (float4*)((char*)d_ws + PK_OFF);
        transpose_kernel<<<dim3(NB * 64), dim3(256), 0, stream>>>(
            xloc, xfeat, ft, pack, (float*)d_out);
        knn_v2_kernel<<<dim3(NB * 64), dim3(256), 0, stream>>>(pack, knn_ws);
        conv_g2_kernel<<<dim3(NB * 256), dim3(128), 0, stream>>>(
            Wrel, brel, Wroot, knn_ws, ft, pack, (float*)d_out);
    } else if (d_ws != nullptr && ws_size >= (size_t)KNN_BYTES) {
        u16* knn_ws = (u16*)d_ws;
        knn_seg8_kernel<<<dim3(NB * 128), dim3(256), 0, stream>>>(xloc, knn_ws);
        conv_q_kernel<<<dim3(NB * 128), dim3(128), 0, stream>>>(
            xloc, xfeat, Wrel, brel, Wroot, knn_ws, (float*)d_out);
    } else {
        pcd_all<<<dim3(NB * N_PTS), dim3(64), 0, stream>>>(
            xloc, xfeat, Wrel, brel, Wroot, (float*)d_out);
    }
}

// Round 17
// 272.997 us; speedup vs baseline: 1.7888x; 1.0460x over previous
//
#include <hip/hip_runtime.h>

#define N_PTS 4096
#define NB    8
#define KNN   20
#define FIN   67
#define COUT  64
#define SEG   8
#define SEGN  (N_PTS / SEG)   // 512 candidates per segment-wave
#define SLOTS 16              // LDS stack slots per thread
#define BT    512             // knn block threads (8 waves)

typedef unsigned short u16;
typedef unsigned int   u32;
typedef unsigned long long u64;

// ws layout (bytes)
#define KNN_BYTES 1310720u                      // 8*4096*20*2
#define FT_OFF    1310720u                      // ft[b][n][64] f32 = 8388608
#define PK_OFF    (FT_OFF + 8388608u)           // pack[b][n] float4 = 524288
#define WS_NEED   (PK_OFF + 524288u)            // 10223616

__device__ __forceinline__ float finf() { return __uint_as_float(0x7f800000u); }

// Order-preserving f32 -> u32 map (total order, matches IEEE < on non-NaN).
__device__ __forceinline__ u32 fmap(float f) {
    u32 b = __float_as_uint(f);
    return b ^ ((u32)((int)b >> 31) | 0x80000000u);
}

// sq = (x*x + y*y) + z*z, all f32, no FMA (matches np op order).
__device__ __forceinline__ float sq_exact(float x, float y, float z) {
#pragma clang fp contract(off)
    float s = (x * x + y * y) + z * z;
    return s;
}

// dist = (sq_i - 2*dot) + sq_j, dot = (x_i*x_j + y_i*y_j) + z_i*z_j, no FMA.
__device__ __forceinline__ float dist_from_sq(float xi, float yi, float zi, float sqi,
                                              float xj, float yj, float zj, float sqj) {
#pragma clang fp contract(off)
    float d0 = xi * xj, d1 = yi * yj, d2 = zi * zj;
    float dot = (d0 + d1) + d2;
    float d = (sqi - 2.0f * dot) + sqj;
    return d;
}

__device__ __forceinline__ float dist_exact(float xi, float yi, float zi, float sqi,
                                            float xj, float yj, float zj) {
#pragma clang fp contract(off)
    float d0 = xi * xj, d1 = yi * yj, d2 = zi * zj;
    float dot = (d0 + d1) + d2;
    float sqj = (xj * xj + yj * yj) + zj * zj;
    float d = (sqi - 2.0f * dot) + sqj;
    return d;
}

// u64 key = fmap(d) << 12 | j  — plain u64 < is EXACT (d, j) lex order.
__device__ __forceinline__ void cswap64(u64& a, u64& b) {
    bool sw = b < a;
    u64 na = sw ? b : a, nb = sw ? a : b;
    a = na; b = nb;
}

// ---------------- Kernel 0: transpose/pack + out0 passthrough ----------------
__global__ __launch_bounds__(256) void transpose_kernel(
    const float* __restrict__ xloc, const float* __restrict__ xfeat,
    float* __restrict__ ft, float4* __restrict__ pack, float* __restrict__ out) {
    __shared__ float tile[64][65];
    const int tid = threadIdx.x;
    const int blk = blockIdx.x;               // b*64 + ntile
    const int b   = blk >> 6;
    const int n0  = (blk & 63) << 6;
    const int tx  = tid & 63, w = tid >> 6;

    if (tid < 48) {
        int idx4 = blk * 48 + tid;            // 512*48 float4 = 98304 f32
        ((float4*)out)[idx4] = ((const float4*)xloc)[idx4];
    }
    if (w == 0) {
        float x = xloc[((size_t)b * 3 + 0) * N_PTS + n0 + tx];
        float y = xloc[((size_t)b * 3 + 1) * N_PTS + n0 + tx];
        float z = xloc[((size_t)b * 3 + 2) * N_PTS + n0 + tx];
        pack[((size_t)b << 12) + n0 + tx] = make_float4(x, y, z, sq_exact(x, y, z));
    }
#pragma unroll
    for (int k = 0; k < 16; ++k) {
        int c = w * 16 + k;
        tile[tx][c] = xfeat[((size_t)(b << 6) + c) * N_PTS + n0 + tx];
    }
    __syncthreads();
#pragma unroll
    for (int k = 0; k < 16; ++k) {
        int n = w * 16 + k;
        ft[(((size_t)(b << 12)) + n0 + n) * 64 + tx] = tile[n][tx];
    }
}

// ---------------- Kernel 1: kNN — 8 waves/block, wave-uniform segments ----------
// Block = 512 threads = 8 waves; wave w = segment w (512 candidates), lane =
// query (64/block). Candidate addresses wave-uniform (scalar loads). Float-only
// gate vs 21st-best distance; u64 key built only under the insert mask; self
// (d == +0.0) compacted out of the exact top-21 at publish. 16 waves/CU
// (round-16 had 8 — the occupancy fix).
__global__ __launch_bounds__(BT) void knn_v3_kernel(
    const float4* __restrict__ pack, u16* __restrict__ knn_out) {
    __shared__ u64 stk[SLOTS][BT];            // 64 KB, bank-free SoA
    __shared__ u64 ext[KNN - SLOTS][BT];      // 16 KB (publish slots 16..19)
    const int tid  = threadIdx.x;
    const int lane = tid & 63;                // query within tile
    const int blk  = blockIdx.x;              // b*64 + qtile
    const int b    = blk >> 6;
    const int tile = blk & 63;
    const int i    = (tile << 6) | lane;
    const float4* pb = pack + ((size_t)b << 12);

    // Wave-uniform segment base -> scalar loads in the hot loop.
    const int segu  = __builtin_amdgcn_readfirstlane(tid >> 6);
    const float4* base = pb + segu * SEGN;

    const float4 qp = pb[i];
    const float xi = qp.x, yi = qp.y, zi = qp.z, sqi = qp.w;

    u64 ld[32];
#pragma unroll
    for (int t = 0; t < 32; ++t) ld[t] = ~0ull;
    float thr = finf();
    int cnt = 0;

    auto merge_stack = [&]() {
        u64 bd[SLOTS];
#pragma unroll
        for (int t = 0; t < SLOTS; ++t) bd[t] = (t < cnt) ? stk[t][tid] : ~0ull;
#pragma unroll
        for (int k = 2; k <= SLOTS; k <<= 1) {
#pragma unroll
            for (int s = k >> 1; s > 0; s >>= 1) {
#pragma unroll
                for (int t = 0; t < SLOTS; ++t) {
                    int l = t ^ s;
                    if (l > t) {
                        if ((t & k) == 0) cswap64(bd[t], bd[l]);
                        else              cswap64(bd[l], bd[t]);
                    }
                }
            }
        }
#pragma unroll
        for (int t = 0; t < SLOTS; ++t) cswap64(ld[31 - t], bd[t]);
#pragma unroll
        for (int k = 16; k >= 1; k >>= 1) {
#pragma unroll
            for (int t = 0; t < 32; ++t) {
                if ((t & k) == 0) cswap64(ld[t], ld[t | k]);
            }
        }
        // thr = distance of the 21st-best (ld[KNN]); guard padding (all-ones).
        u32 m = (u32)(ld[KNN] >> 12);
        u32 db = m ^ ((m & 0x80000000u) ? 0x80000000u : 0xFFFFFFFFu);
        thr = (m == 0xFFFFFFFFu) ? finf() : __uint_as_float(db);
        cnt = 0;
    };

    const int jbase = segu * SEGN;
    for (int c = 0; c < SEGN; c += 4) {
        float4 p0 = base[c + 0], p1 = base[c + 1];
        float4 p2 = base[c + 2], p3 = base[c + 3];
#pragma unroll
        for (int qq = 0; qq < 4; ++qq) {
            float4 pk = (qq == 0) ? p0 : (qq == 1) ? p1 : (qq == 2) ? p2 : p3;
            float d = dist_from_sq(xi, yi, zi, sqi, pk.x, pk.y, pk.z, pk.w);
            // Float-only gate vs 21st-best: a rejected d == thr candidate has
            // larger j (ascending scan) => key rank > 21 forever. Self is NOT
            // excluded here (d_self == +0.0 inserts; filtered at publish).
            if (d < thr) {
                u64 key = ((u64)fmap(d) << 12) | (u32)(jbase + c + qq);
                stk[cnt][tid] = key;
                ++cnt;
            }
        }
        // Entering a chunk all lanes have cnt <= 12; +4 max => <= 16. ✓
        if (__any(cnt >= SLOTS - 3)) merge_stack();
    }
    merge_stack();                            // drain

    // Publish exact top-20 EXCLUDING self: compact ld[0..20] (exact top-21).
    u64 pub[KNN];
    {
        bool sf = false;
#pragma unroll
        for (int t = 0; t < KNN + 1; ++t) {
            bool isself = ((u32)(ld[t] & 0xFFFull) == (u32)i);
            sf = sf || isself;
            if (t < KNN) pub[t] = sf ? ld[t + 1] : ld[t];
        }
    }
#pragma unroll
    for (int t = 0; t < SLOTS; ++t) stk[t][tid] = pub[t];
#pragma unroll
    for (int t = SLOTS; t < KNN; ++t) ext[t - SLOTS][tid] = pub[t];
    __syncthreads();

    // Exact 8-way tournament merge per query (threads 0..63).
    if (tid < 64) {
        const int q = tid;
        const int row = (b << 12) | (tile << 6) | q;
        int pp[SEG];
        u64 kk[SEG];
#pragma unroll
        for (int s = 0; s < SEG; ++s) { pp[s] = 0; kk[s] = stk[0][q + 64 * s]; }
#pragma unroll
        for (int t = 0; t < KNN; ++t) {
            u64 best = kk[0]; int sm = 0;
#pragma unroll
            for (int s = 1; s < SEG; ++s)
                if (kk[s] < best) { best = kk[s]; sm = s; }
            knn_out[(size_t)row * KNN + t] = (u16)(best & 0xFFFull);
#pragma unroll
            for (int s = 0; s < SEG; ++s) {
                if (s == sm) {
                    int p = ++pp[s];
                    int col = q + 64 * s;
                    kk[s] = (p < KNN) ? ((p < SLOTS) ? stk[p][col] : ext[p - SLOTS][col])
                                      : ~0ull;
                }
            }
        }
    }
}

// ---------------- Kernel 2: conv — 16-pt tiles, LDS index preload ----------------
__global__ __launch_bounds__(128) void conv_g2_kernel(
    const float* __restrict__ Wrel,
    const float* __restrict__ brel,
    const float* __restrict__ Wroot,
    const u16* __restrict__ knn_in,
    const float* __restrict__ ft,
    const float4* __restrict__ pack,
    float* __restrict__ out) {
    __shared__ float aggf[16][69];
    __shared__ float hif[16][69];
    __shared__ u16 idx[16 * KNN];             // 640 B
    const int tid = threadIdx.x;
    const int blk = blockIdx.x;               // b*256 + tile
    const int b   = blk >> 8;
    const int i0  = (blk & 255) << 4;
    const int lane = tid & 63, w = tid >> 6;
    const float* ftb = ft + (((size_t)b << 12)) * 64;
    const float* pkb = (const float*)(pack + ((size_t)b << 12));

    {
        const u32* src = (const u32*)(knn_in + (size_t)((b << 12) | i0) * KNN);
        for (int k = tid; k < 16 * KNN / 2; k += 128) ((u32*)idx)[k] = src[k];
    }
    __syncthreads();

#pragma unroll
    for (int pp = 0; pp < 8; ++pp) {
        int p = w * 8 + pp;
        int i = i0 + p;
        float af = 0.f, al = 0.f;
        float hfv = ftb[(size_t)i * 64 + lane];
        float hlv = (lane < 3) ? pkb[(size_t)i * 4 + lane] : 0.f;
#pragma unroll
        for (int t = 0; t < KNN; ++t) {       // ascending (dist, idx) order
            int j = idx[p * KNN + t];
            af += ftb[(size_t)j * 64 + lane];
            if (lane < 3) al += pkb[(size_t)j * 4 + lane];
        }
        aggf[p][3 + lane] = af;
        hif[p][3 + lane]  = hfv;
        if (lane < 3) { aggf[p][lane] = al; hif[p][lane] = hlv; }
    }
    __syncthreads();

    const int p2 = tid & 15, oct = tid >> 4;  // 8 channels per thread
    const int i2 = i0 + p2;
    float rel[8], root[8];
#pragma unroll
    for (int c = 0; c < 8; ++c) { rel[c] = 0.f; root[c] = 0.f; }
    for (int f = 0; f < FIN; ++f) {
        float a = aggf[p2][f];
        float h = hif[p2][f];
        const float4* w4r = (const float4*)(Wrel + f * COUT + oct * 8);
        const float4* w4o = (const float4*)(Wroot + f * COUT + oct * 8);
#pragma unroll
        for (int c4 = 0; c4 < 2; ++c4) {
            float4 wr = w4r[c4], wo = w4o[c4];
            rel[c4 * 4 + 0] += a * wr.x;  root[c4 * 4 + 0] += h * wo.x;
            rel[c4 * 4 + 1] += a * wr.y;  root[c4 * 4 + 1] += h * wo.y;
            rel[c4 * 4 + 2] += a * wr.z;  root[c4 * 4 + 2] += h * wo.z;
            rel[c4 * 4 + 3] += a * wr.w;  root[c4 * 4 + 3] += h * wo.w;
        }
    }
    const size_t ob = (size_t)NB * 3 * N_PTS + (size_t)b * COUT * N_PTS;
#pragma unroll
    for (int c = 0; c < 8; ++c) {
        int cc = oct * 8 + c;
        float acc = (rel[c] + brel[cc]) + root[c];  // einsum + b_rel + einsum order
        out[ob + (size_t)cc * N_PTS + i2] = fmaxf(acc, 0.f);
    }
}

// ================= r14 fallback path (proven, 379us) =================
__global__ __launch_bounds__(256) void knn_seg8_kernel(
    const float* __restrict__ xloc, u16* __restrict__ knn_out) {
    __shared__ u64 stk[SLOTS][256];
    __shared__ u64 ext[KNN - SLOTS][256];
    const int tid  = threadIdx.x;
    const int q    = tid & 31;
    const int seg  = tid >> 5;
    const int blk  = blockIdx.x;
    const int b    = blk >> 7;
    const int i    = ((blk & 127) << 5) | q;
    const float* xb = xloc + (size_t)b * 3 * N_PTS;

    const float xi = xb[i], yi = xb[N_PTS + i], zi = xb[2 * N_PTS + i];
    const float sqi = sq_exact(xi, yi, zi);

    u64 ld[32];
#pragma unroll
    for (int t = 0; t < 32; ++t) ld[t] = ~0ull;
    u64 thr = ~0ull;
    int cnt = 0;

    auto merge_stack = [&]() {
        u64 bd[SLOTS];
#pragma unroll
        for (int t = 0; t < SLOTS; ++t) bd[t] = (t < cnt) ? stk[t][tid] : ~0ull;
#pragma unroll
        for (int k = 2; k <= SLOTS; k <<= 1) {
#pragma unroll
            for (int s = k >> 1; s > 0; s >>= 1) {
#pragma unroll
                for (int t = 0; t < SLOTS; ++t) {
                    int l = t ^ s;
                    if (l > t) {
                        if ((t & k) == 0) cswap64(bd[t], bd[l]);
                        else              cswap64(bd[l], bd[t]);
                    }
                }
            }
        }
#pragma unroll
        for (int t = 0; t < SLOTS; ++t) cswap64(ld[31 - t], bd[t]);
#pragma unroll
        for (int k = 16; k >= 1; k >>= 1) {
#pragma unroll
            for (int t = 0; t < 32; ++t) {
                if ((t & k) == 0) cswap64(ld[t], ld[t | k]);
            }
        }
        thr = ld[KNN - 1];
        cnt = 0;
    };

    const int cbase = seg * 512;
    for (int c = 0; c < 512; c += 4) {
        const int cc = cbase + c;
        float4 fx = *(const float4*)(xb + cc);
        float4 fy = *(const float4*)(xb + N_PTS + cc);
        float4 fz = *(const float4*)(xb + 2 * N_PTS + cc);
#pragma unroll
        for (int qq = 0; qq < 4; ++qq) {
            float xj = (qq == 0) ? fx.x : (qq == 1) ? fx.y : (qq == 2) ? fx.z : fx.w;
            float yj = (qq == 0) ? fy.x : (qq == 1) ? fy.y : (qq == 2) ? fy.z : fy.w;
            float zj = (qq == 0) ? fz.x : (qq == 1) ? fz.y : (qq == 2) ? fz.z : fz.w;
            float sqj = sq_exact(xj, yj, zj);
            float d = dist_from_sq(xi, yi, zi, sqi, xj, yj, zj, sqj);
            int j = cc + qq;
            u64 key = ((u64)fmap(d) << 12) | (u32)j;
            bool ok = (j != i) && (key < thr);
            if (ok) { stk[cnt][tid] = key; ++cnt; }
        }
        if (__any(cnt >= SLOTS - 3)) merge_stack();
    }
    merge_stack();

#pragma unroll
    for (int t = 0; t < SLOTS; ++t) stk[t][tid] = ld[t];
#pragma unroll
    for (int t = SLOTS; t < KNN; ++t) ext[t - SLOTS][tid] = ld[t];
    __syncthreads();

    if (tid < 32) {
        const int col0 = tid;
        const int row  = (b << 12) | ((blk & 127) << 5) | tid;
        int  pp[8];
        u64  kk[8];
#pragma unroll
        for (int s = 0; s < 8; ++s) { pp[s] = 0; kk[s] = stk[0][col0 + 32 * s]; }
#pragma unroll
        for (int t = 0; t < KNN; ++t) {
            u64 best = kk[0]; int sm = 0;
#pragma unroll
            for (int s = 1; s < 8; ++s)
                if (kk[s] < best) { best = kk[s]; sm = s; }
            knn_out[(size_t)row * KNN + t] = (u16)(best & 0xFFFu);
#pragma unroll
            for (int s = 0; s < 8; ++s) {
                if (s == sm) {
                    int p = ++pp[s];
                    int col = col0 + 32 * s;
                    kk[s] = (p < KNN) ? ((p < SLOTS) ? stk[p][col] : ext[p - SLOTS][col])
                                      : ~0ull;
                }
            }
        }
    }
}

__global__ __launch_bounds__(128) void conv_q_kernel(
    const float* __restrict__ xloc,
    const float* __restrict__ xfeat,
    const float* __restrict__ Wrel,
    const float* __restrict__ brel,
    const float* __restrict__ Wroot,
    const u16* __restrict__ knn_in,
    float* __restrict__ out) {
    __shared__ float rowbuf[2][N_PTS];
    const int tid = threadIdx.x;
    const int p   = tid & 31;
    const int qtr = tid >> 5;
    const int blk = blockIdx.x;
    const int b   = blk >> 7;
    const int i   = ((blk & 127) << 5) | p;
    const float* xb = xloc + (size_t)b * 3 * N_PTS;
    const float* fb = xfeat + (size_t)b * 64 * N_PTS;

    if (qtr == 0) {
#pragma unroll
        for (int c = 0; c < 3; ++c)
            out[((size_t)b * 3 + c) * N_PTS + i] = xb[(size_t)c * N_PTS + i];
    }

    u32 kl[KNN / 2];
    const u32* kp = (const u32*)(knn_in + (size_t)((b << 12) | i) * KNN);
#pragma unroll
    for (int w = 0; w < KNN / 2; ++w) kl[w] = kp[w];
    int jj[KNN];
#pragma unroll
    for (int t = 0; t < KNN; ++t) jj[t] = (int)((kl[t >> 1] >> ((t & 1) * 16)) & 0xFFFFu);

    float rel[16], root[16];
#pragma unroll
    for (int c = 0; c < 16; ++c) { rel[c] = 0.f; root[c] = 0.f; }

    auto stage = [&](int f) {
        const float* src = (f < 3) ? (xb + (size_t)f * N_PTS)
                                   : (fb + (size_t)(f - 3) * N_PTS);
        const float4* s4 = (const float4*)src;
        float4* d4 = (float4*)rowbuf[f & 1];
#pragma unroll
        for (int w = 0; w < 8; ++w) {
            int idxw = w * 128 + tid;
            d4[idxw] = s4[idxw];
        }
    };

    stage(0);
    __syncthreads();

    for (int f = 0; f < FIN; ++f) {
        if (f + 1 < FIN) stage(f + 1);
        const float* cur = rowbuf[f & 1];
        float hf = cur[i];
        float af = 0.f;
#pragma unroll
        for (int t = 0; t < KNN; ++t) af += cur[jj[t]];

        const float4* w4r = (const float4*)(Wrel + f * COUT + qtr * 16);
        const float4* w4o = (const float4*)(Wroot + f * COUT + qtr * 16);
#pragma unroll
        for (int c4 = 0; c4 < 4; ++c4) {
            float4 wr = w4r[c4], wo = w4o[c4];
            rel[c4 * 4 + 0] += af * wr.x;  root[c4 * 4 + 0] += hf * wo.x;
            rel[c4 * 4 + 1] += af * wr.y;  root[c4 * 4 + 1] += hf * wo.y;
            rel[c4 * 4 + 2] += af * wr.z;  root[c4 * 4 + 2] += hf * wo.z;
            rel[c4 * 4 + 3] += af * wr.w;  root[c4 * 4 + 3] += hf * wo.w;
        }
        __syncthreads();
    }

    const size_t ob = (size_t)NB * 3 * N_PTS + (size_t)b * COUT * N_PTS;
#pragma unroll
    for (int c = 0; c < 16; ++c) {
        int cc = qtr * 16 + c;
        float acc = (rel[c] + brel[cc]) + root[c];
        out[ob + (size_t)cc * N_PTS + i] = fmaxf(acc, 0.f);
    }
}

// ---------------- Last-resort fallback: proven round-7 monolith ----------------
__device__ __forceinline__ void insert3(float d, int c,
                                        float& v0, float& v1, float& v2,
                                        int& c0, int& c1, int& c2) {
    if (d < v2) {
        if (d < v1) {
            if (d < v0) { v2 = v1; c2 = c1; v1 = v0; c1 = c0; v0 = d; c0 = c; }
            else        { v2 = v1; c2 = c1; v1 = d;  c1 = c; }
        } else          { v2 = d;  c2 = c; }
    }
}

__global__ __launch_bounds__(64) void pcd_all(
    const float* __restrict__ xloc,
    const float* __restrict__ xfeat,
    const float* __restrict__ Wrel,
    const float* __restrict__ brel,
    const float* __restrict__ Wroot,
    float* __restrict__ out) {
    const int lane = threadIdx.x;
    const int row  = blockIdx.x;
    const int b    = row >> 12;
    const int i    = row & (N_PTS - 1);
    const float* xb = xloc + (size_t)b * 3 * N_PTS;

    if (lane < 3) {
        out[((size_t)b * 3 + lane) * N_PTS + i] = xb[(size_t)lane * N_PTS + i];
    }

    const float xi  = xb[i];
    const float yi  = xb[N_PTS + i];
    const float zi  = xb[2 * N_PTS + i];
    const float sqi = sq_exact(xi, yi, zi);

    float v0 = 1e30f, v1 = 1e30f, v2 = 1e30f;
    int   c0 = -1,    c1 = -1,    c2 = -1;

    for (int s = 0; s < 16; ++s) {
        int jb = s * 256 + lane * 4;
        float4 fx = *(const float4*)(xb + jb);
        float4 fy = *(const float4*)(xb + N_PTS + jb);
        float4 fz = *(const float4*)(xb + 2 * N_PTS + jb);
#pragma unroll
        for (int q = 0; q < 4; ++q) {
            float xj = (q == 0) ? fx.x : (q == 1) ? fx.y : (q == 2) ? fx.z : fx.w;
            float yj = (q == 0) ? fy.x : (q == 1) ? fy.y : (q == 2) ? fy.z : fy.w;
            float zj = (q == 0) ? fz.x : (q == 1) ? fz.y : (q == 2) ? fz.z : fz.w;
            int j = jb + q;
            float d = (j == i) ? 1e30f : dist_exact(xi, yi, zi, sqi, xj, yj, zj);
            insert3(d, s * 4 + q, v0, v1, v2, c0, c1, c2);
        }
    }

    u64 taken = 0;
    __shared__ int knn[KNN];

    for (int t = 0; t < KNN; ++t) {
        float bv = v0;
        int   bj = (c0 >= 0) ? (((c0 >> 2) << 8) + lane * 4 + (c0 & 3)) : (N_PTS - 1);
#pragma unroll
        for (int m = 1; m < 64; m <<= 1) {
            float ov = __shfl_xor(bv, m);
            int   oj = __shfl_xor(bj, m);
            if (ov < bv || (ov == bv && oj < bj)) { bv = ov; bj = oj; }
        }
        if (lane == 0) knn[t] = bj & (N_PTS - 1);
        int owner = (bj >> 2) & 63;
        if (lane == owner) {
            int cw = (((bj >> 8) << 2) | (bj & 3)) & 63;
            taken |= (1ull << cw);
            v0 = v1; c0 = c1; v1 = v2; c1 = c2; v2 = 1e30f; c2 = -1;
            if (v0 >= 1e30f) {
                v0 = v1 = v2 = 1e30f; c0 = c1 = c2 = -1;
                for (int s = 0; s < 16; ++s) {
                    int jb = s * 256 + lane * 4;
                    float4 fx = *(const float4*)(xb + jb);
                    float4 fy = *(const float4*)(xb + N_PTS + jb);
                    float4 fz = *(const float4*)(xb + 2 * N_PTS + jb);
#pragma unroll
                    for (int q = 0; q < 4; ++q) {
                        int cc = s * 4 + q;
                        if ((taken >> cc) & 1ull) continue;
                        int j = jb + q;
                        if (j == i) continue;
                        float xj = (q == 0) ? fx.x : (q == 1) ? fx.y : (q == 2) ? fx.z : fx.w;
                        float yj = (q == 0) ? fy.x : (q == 1) ? fy.y : (q == 2) ? fy.z : fy.w;
                        float zj = (q == 0) ? fz.x : (q == 1) ? fz.y : (q == 2) ? fz.z : fz.w;
                        float d = dist_exact(xi, yi, zi, sqi, xj, yj, zj);
                        insert3(d, cc, v0, v1, v2, c0, c1, c2);
                    }
                }
            }
        }
    }

    __syncthreads();

    __shared__ float aggf[FIN + 1];
    __shared__ float hif[FIN + 1];

    const float* xfb = xfeat + ((size_t)b * 64 + lane) * N_PTS;
    const float* xlb = xb + (size_t)(lane < 3 ? lane : 0) * N_PTS;
    float af = 0.f, al = 0.f;
    for (int t = 0; t < KNN; ++t) {
        int j = knn[t];
        af += xfb[j];
        if (lane < 3) al += xlb[j];
    }
    aggf[3 + lane] = af;
    hif[3 + lane]  = xfb[i];
    if (lane < 3) { aggf[lane] = al; hif[lane] = xlb[i]; }
    __syncthreads();

    float acc_rel = 0.f, acc_root = 0.f;
    for (int f = 0; f < FIN; ++f) {
        acc_rel  += aggf[f] * Wrel[f * COUT + lane];
        acc_root += hif[f]  * Wroot[f * COUT + lane];
    }
    float acc = (acc_rel + brel[lane]) + acc_root;
    acc = fmaxf(acc, 0.0f);
    out[(size_t)NB * 3 * N_PTS + ((((size_t)b << 6) | lane) << 12) + i] = acc;
}

extern "C" void kernel_launch(void* const* d_in, const int* in_sizes, int n_in,
                              void* d_out, int out_size, void* d_ws, size_t ws_size,
                              hipStream_t stream) {
    const float* xloc  = nullptr;
    const float* xfeat = nullptr;
    const float* Wrel  = nullptr;
    const float* brel  = nullptr;
    const float* Wroot = nullptr;
    for (int idx = 0; idx < n_in; ++idx) {
        const long long s = in_sizes[idx];
        const float* p = (const float*)d_in[idx];
        if (s == 98304LL || s == 393216LL)          { xloc = p; }
        else if (s == 2097152LL || s == 8388608LL)  { xfeat = p; }
        else if (s == 4288LL || s == 17152LL)       { if (!Wrel) Wrel = p; else Wroot = p; }
        else if (s == 64LL || s == 256LL)           { brel = p; }
    }
    if (!xloc || !xfeat || !Wrel || !brel || !Wroot) {
        xloc  = (const float*)d_in[0];
        xfeat = (const float*)d_in[1];
        Wrel  = (const float*)d_in[2];
        brel  = (const float*)d_in[3];
        Wroot = (const float*)d_in[4];
    }

    if (d_ws != nullptr && ws_size >= (size_t)WS_NEED) {
        u16*    knn_ws = (u16*)d_ws;
        float*  ft     = (float*)((char*)d_ws + FT_OFF);
        float4* pack   = (float4*)((char*)d_ws + PK_OFF);
        transpose_kernel<<<dim3(NB * 64), dim3(256), 0, stream>>>(
            xloc, xfeat, ft, pack, (float*)d_out);
        knn_v3_kernel<<<dim3(NB * 64), dim3(BT), 0, stream>>>(pack, knn_ws);
        conv_g2_kernel<<<dim3(NB * 256), dim3(128), 0, stream>>>(
            Wrel, brel, Wroot, knn_ws, ft, pack, (float*)d_out);
    } else if (d_ws != nullptr && ws_size >= (size_t)KNN_BYTES) {
        u16* knn_ws = (u16*)d_ws;
        knn_seg8_kernel<<<dim3(NB * 128), dim3(256), 0, stream>>>(xloc, knn_ws);
        conv_q_kernel<<<dim3(NB * 128), dim3(128), 0, stream>>>(
            xloc, xfeat, Wrel, brel, Wroot, knn_ws, (float*)d_out);
    } else {
        pcd_all<<<dim3(NB * N_PTS), dim3(64), 0, stream>>>(
            xloc, xfeat, Wrel, brel, Wroot, (float*)d_out);
    }
}